// Round 7
// baseline (339.365 us; speedup 1.0000x reference)
//
#include <hip/hip_runtime.h>
#include <math.h>

#define B_   256
#define IN_  512
#define C_   4
#define M_   6
#define K_   64
#define S1_  255
#define S2_  63

#define NBLK1 (C_ * S1_)                 // 1020
#define NBLK2 (C_ * S2_)                 // 252
#define NBLK3 (C_)                       // 4
#define NBLK_ALL (NBLK1 + NBLK2 + NBLK3) // 1276

#define LMIN_ (-6.906754778648554f)
#define LMAX_ ( 6.906754778648554f)
#define LR_   0.001f
#define WCLIP_ 5.0f

__device__ __forceinline__ float clampf(float v, float lo, float hi) {
    return fminf(fmaxf(v, lo), hi);
}

// One-time prep: xT[i][b], l0[b][i]; bias columns of out1RM/out2RM.
__global__ __launch_bounds__(256) void prep_kernel(const float* __restrict__ x,
                                                   const float* __restrict__ bias1,
                                                   const float* __restrict__ bias2,
                                                   float* __restrict__ xT,
                                                   float* __restrict__ l0,
                                                   float* __restrict__ out1RM,
                                                   float* __restrict__ out2RM) {
    __shared__ float tx_[32][33];
    const int i0 = (blockIdx.x & 15) * 32;
    const int b0 = (blockIdx.x >> 4) * 32;
    const int tx = threadIdx.x & 31;
    const int ty = threadIdx.x >> 5;
#pragma unroll
    for (int r = 0; r < 4; ++r) {
        int bb = b0 + ty + 8 * r;
        int ii = i0 + tx;
        float xv = x[(size_t)bb * IN_ + ii];
        float xc = clampf(xv, 0.001f, 0.999f);
        float lv = (ii == 0) ? 0.0f : logf(xc / (1.0f - xc));
        l0[(size_t)bb * IN_ + ii] = lv;
        tx_[ty + 8 * r][tx] = xv;
    }
    __syncthreads();
#pragma unroll
    for (int r = 0; r < 4; ++r) {
        int ii = i0 + ty + 8 * r;
        int bb = b0 + tx;
        xT[(size_t)ii * B_ + bb] = tx_[tx][ty + 8 * r];
    }
    int gid = blockIdx.x * 256 + threadIdx.x;
    if (gid < C_ * B_) {
        int c = gid >> 8, b = gid & 255;
        out1RM[((size_t)c * B_ + b) * (S1_ + 1)] = bias1[c];
        out2RM[((size_t)c * B_ + b) * (S2_ + 1)] = bias2[c];
    }
}

// Routing: 512 threads = 2 tiles x 2 k-halves; thread -> (half, b).
__global__ __launch_bounds__(512) void route_kernel(
    const float* __restrict__ xT,       // [IN][B]
    const float* __restrict__ cmaps1,
    const float* __restrict__ cmaps2,
    const float* __restrict__ cmaps3,
    int* __restrict__ idx_buf)          // [NBLK_ALL][B]
{
    __shared__ float sacc[2][M_][B_];   // 12 KB
    const int tid  = threadIdx.x;
    const int half = tid >> 8;          // k-half, wave-uniform
    const int b    = tid & 255;
    const int t0   = blockIdx.x * 2;

    const float* cmp[2];
#pragma unroll
    for (int u = 0; u < 2; ++u) {
        int bid = t0 + u;
        const float* base;
        if (bid < NBLK1)              base = cmaps1 + (size_t)bid * M_ * IN_;
        else if (bid < NBLK1 + NBLK2) base = cmaps2 + (size_t)(bid - NBLK1) * M_ * IN_;
        else                          base = cmaps3 + (size_t)(bid - NBLK1 - NBLK2) * M_ * IN_;
        cmp[u] = base + half * 256;
    }

    float acc[2][M_];
#pragma unroll
    for (int u = 0; u < 2; ++u)
#pragma unroll
        for (int m = 0; m < M_; ++m) acc[u][m] = 0.0f;

    const float* xk = xT + (size_t)(half * 256) * B_ + b;
    for (int k = 0; k < 256; k += 8) {
        float xv[8];
#pragma unroll
        for (int j = 0; j < 8; ++j) xv[j] = xk[(size_t)(k + j) * B_];
#pragma unroll
        for (int j = 0; j < 8; ++j)
#pragma unroll
            for (int u = 0; u < 2; ++u)
#pragma unroll
                for (int m = 0; m < M_; ++m)
                    acc[u][m] = fmaf(cmp[u][(size_t)m * IN_ + k + j], xv[j], acc[u][m]);
    }

    if (half == 1) {
#pragma unroll
        for (int u = 0; u < 2; ++u)
#pragma unroll
            for (int m = 0; m < M_; ++m) sacc[u][m][b] = acc[u][m];
    }
    __syncthreads();
    if (half == 0) {
#pragma unroll
        for (int u = 0; u < 2; ++u) {
            int myidx = 0;
#pragma unroll
            for (int m = 0; m < M_; ++m) {
                float t = acc[u][m] + sacc[u][m][b];
                myidx |= (t > 0.0f) ? (1 << m) : 0;
            }
            idx_buf[(size_t)(t0 + u) * B_ + b] = myidx;
        }
    }
}

// Partial dot: block = (tile, 64-wide k-slice). lg segment in registers,
// w slice staged once in LDS (pad 65 -> conflict-free gather). One barrier.
template<int DIN, int KSPL>
__global__ __launch_bounds__(256) void dot_kernel(
    const float* __restrict__ lgRM, long lg_sc,
    const float* __restrict__ w,
    const int* __restrict__ idx_buf,
    float* __restrict__ pdot,          // [tiles][KSPL][B]
    int S)
{
    constexpr int KR = DIN / KSPL;     // = 64
    static_assert(KR == 64, "k-slice must be 64");
    __shared__ float wl[K_][KR + 1];

    const int bid  = blockIdx.x;
    const int tile = bid / KSPL;
    const int ks   = bid % KSPL;
    const int c    = tile / S;
    const int tid  = threadIdx.x;
    const int b    = tid;
    const int k0   = ks * KR;

    // lg row segment -> 16 float4 regs (per-lane contiguous, L1/L2-hot)
    const float* lgr = lgRM + (size_t)c * lg_sc + (size_t)b * DIN + k0;
    float4 lgv[16];
#pragma unroll
    for (int j = 0; j < 16; ++j) lgv[j] = *(const float4*)(lgr + 4 * j);

    // stage w 64x64 slice (coalesced f4), 4 per thread
    const float* wp = w + (size_t)tile * K_ * DIN + k0;
#pragma unroll
    for (int j = 0; j < 4; ++j) {
        int f   = tid + 256 * j;
        int row = f >> 4;
        int q   = (f & 15) << 2;
        float4 v = *(const float4*)(wp + (size_t)row * DIN + q);
        wl[row][q + 0] = v.x;
        wl[row][q + 1] = v.y;
        wl[row][q + 2] = v.z;
        wl[row][q + 3] = v.w;
    }
    const int myrow = idx_buf[(size_t)tile * B_ + b];
    __syncthreads();

    float dot = 0.0f;
#pragma unroll
    for (int j = 0; j < 16; ++j) {
        dot = fmaf(wl[myrow][4 * j + 0], lgv[j].x, dot);
        dot = fmaf(wl[myrow][4 * j + 1], lgv[j].y, dot);
        dot = fmaf(wl[myrow][4 * j + 2], lgv[j].z, dot);
        dot = fmaf(wl[myrow][4 * j + 3], lgv[j].w, dot);
    }
    pdot[((size_t)tile * KSPL + ks) * B_ + b] = dot;
}

// Finalize: sum partials (fixed order), clip, outputs, diff, winner, dw.
__global__ __launch_bounds__(256) void fin_kernel(
    const float* __restrict__ pdot, int KSPL,
    const int* __restrict__ idx_buf,
    const int* __restrict__ target,
    float* __restrict__ onextRM,       // [c][b][S+1] or logits[b][C]
    int* __restrict__ win_g,           // [tiles][K]
    float* __restrict__ dw_g,          // [tiles][K]
    int S, int is_last)
{
    __shared__ float diff_s[B_];
    __shared__ int   win_s[K_];
    const int tile = blockIdx.x;
    const int c    = tile / S;
    const int s    = tile - c * S;
    const int b    = threadIdx.x;

    if (b < K_) win_s[b] = -1;

    float dot = 0.0f;
    for (int j = 0; j < KSPL; ++j)
        dot += pdot[((size_t)tile * KSPL + j) * B_ + b];

    float outv = clampf(dot, LMIN_, LMAX_);
    if (is_last) onextRM[(size_t)b * C_ + c] = outv;
    else         onextRM[((size_t)c * B_ + b) * (size_t)(S + 1) + (s + 1)] = outv;

    float tg = (target[b] == c) ? 1.0f : 0.0f;
    diff_s[b] = 1.0f / (1.0f + expf(-outv)) - tg;
    const int myrow = idx_buf[(size_t)tile * B_ + b];
    __syncthreads();
    atomicMax(&win_s[myrow], b);         // last-b-wins == max b
    __syncthreads();
    if (b < K_) {
        int bw = win_s[b];
        win_g[(size_t)tile * K_ + b] = bw;
        dw_g[(size_t)tile * K_ + b]  = (bw >= 0) ? LR_ * diff_s[bw] : 0.0f;
    }
}

// Stream update: thread -> 8 float4.
template<int DIN>
__global__ __launch_bounds__(256) void update_kernel(
    const float* __restrict__ w,
    const float* __restrict__ lgRM, long lg_sc,
    const int* __restrict__ win_g,
    const float* __restrict__ dw_g,
    float* __restrict__ nw,
    int SK)                            // S * K_ (rows per class)
{
    constexpr int QPR = DIN / 4;
    constexpr int QSH = (DIN == 512) ? 7 : (DIN == 256) ? 6 : 4;
    const int base = blockIdx.x * 2048 + threadIdx.x;
#pragma unroll
    for (int j = 0; j < 8; ++j) {
        int Q   = base + j * 256;
        int row = Q >> QSH;
        int col = (Q & (QPR - 1)) << 2;
        float4 wv = *(const float4*)(w + (size_t)row * DIN + col);
        int bw = win_g[row];
        if (bw >= 0) {
            float d = dw_g[row];
            int cc  = row / SK;
            const float4 lv = *(const float4*)(lgRM + (size_t)cc * lg_sc + (size_t)bw * DIN + col);
            wv.x = clampf(wv.x - d * lv.x, -WCLIP_, WCLIP_);
            wv.y = clampf(wv.y - d * lv.y, -WCLIP_, WCLIP_);
            wv.z = clampf(wv.z - d * lv.z, -WCLIP_, WCLIP_);
            wv.w = clampf(wv.w - d * lv.w, -WCLIP_, WCLIP_);
        }
        *(float4*)(nw + (size_t)row * DIN + col) = wv;
    }
}

extern "C" void kernel_launch(void* const* d_in, const int* in_sizes, int n_in,
                              void* d_out, int out_size, void* d_ws, size_t ws_size,
                              hipStream_t stream) {
    const float* x      = (const float*)d_in[0];
    const int*   target = (const int*)  d_in[1];
    const float* cmaps1 = (const float*)d_in[2];
    const float* w1     = (const float*)d_in[3];
    const float* bias1  = (const float*)d_in[4];
    const float* cmaps2 = (const float*)d_in[5];
    const float* w2     = (const float*)d_in[6];
    const float* bias2  = (const float*)d_in[7];
    const float* cmaps3 = (const float*)d_in[8];
    const float* w3     = (const float*)d_in[9];
    float* out = (float*)d_out;

    float* xT      = (float*)d_ws;                           // 131072
    float* l0      = xT     + (size_t)IN_ * B_;              // 131072
    float* out1RM  = l0     + (size_t)B_ * IN_;              // 262144
    float* out2RM  = out1RM + (size_t)C_ * B_ * (S1_ + 1);   // 65536
    float* pdot    = out2RM + (size_t)C_ * B_ * (S2_ + 1);   // NBLK1*8*B = 2088960
    float* dw_g    = pdot   + (size_t)NBLK1 * 8 * B_;        // NBLK_ALL*K
    int*   win_g   = (int*)(dw_g + (size_t)NBLK_ALL * K_);   // NBLK_ALL*K
    int*   idx_buf = (int*)(win_g + (size_t)NBLK_ALL * K_);  // NBLK_ALL*B

    float* logits = out;
    float* nw1 = out + (size_t)B_ * C_;
    float* nw2 = nw1 + (size_t)C_ * S1_ * K_ * IN_;
    float* nw3 = nw2 + (size_t)C_ * S2_ * K_ * (S1_ + 1);

    prep_kernel<<<dim3(128), dim3(256), 0, stream>>>(
        x, bias1, bias2, xT, l0, out1RM, out2RM);

    route_kernel<<<dim3(NBLK_ALL / 2), dim3(512), 0, stream>>>(
        xT, cmaps1, cmaps2, cmaps3, idx_buf);

    const int* idx1 = idx_buf;
    const int* idx2 = idx_buf + (size_t)NBLK1 * B_;
    const int* idx3 = idx_buf + (size_t)(NBLK1 + NBLK2) * B_;
    int*   win1 = win_g;                         float* dw1 = dw_g;
    int*   win2 = win_g + NBLK1 * K_;            float* dw2 = dw_g + NBLK1 * K_;
    int*   win3 = win_g + (NBLK1 + NBLK2) * K_;  float* dw3 = dw_g + (NBLK1 + NBLK2) * K_;

    // ---- layer 1 (DIN=512, lg = l0, c-stride 0) ----
    dot_kernel<512, 8><<<dim3(NBLK1 * 8), dim3(256), 0, stream>>>(
        l0, 0L, w1, idx1, pdot, S1_);
    fin_kernel<<<dim3(NBLK1), dim3(256), 0, stream>>>(
        pdot, 8, idx1, target, out1RM, win1, dw1, S1_, 0);
    update_kernel<512><<<dim3(NBLK1 * K_ * 128 / 2048), dim3(256), 0, stream>>>(
        w1, l0, 0L, win1, dw1, nw1, S1_ * K_);

    // ---- layer 2 (DIN=256, lg = out1RM) ----
    dot_kernel<256, 4><<<dim3(NBLK2 * 4), dim3(256), 0, stream>>>(
        out1RM, (long)B_ * (S1_ + 1), w2, idx2, pdot, S2_);
    fin_kernel<<<dim3(NBLK2), dim3(256), 0, stream>>>(
        pdot, 4, idx2, target, out2RM, win2, dw2, S2_, 0);
    update_kernel<256><<<dim3(NBLK2 * K_ * 64 / 2048), dim3(256), 0, stream>>>(
        w2, out1RM, (long)B_ * (S1_ + 1), win2, dw2, nw2, S2_ * K_);

    // ---- layer 3 (DIN=64, lg = out2RM) ----
    dot_kernel<64, 1><<<dim3(NBLK3), dim3(256), 0, stream>>>(
        out2RM, (long)B_ * (S2_ + 1), w3, idx3, pdot, 1);
    fin_kernel<<<dim3(NBLK3), dim3(256), 0, stream>>>(
        pdot, 1, idx3, target, logits, win3, dw3, 1, 1);
    update_kernel<64><<<dim3(NBLK3 * K_ * 16 / 2048), dim3(256), 0, stream>>>(
        w3, out2RM, (long)B_ * (S2_ + 1), win3, dw3, nw3, K_);
}

// Round 8
// 283.165 us; speedup vs baseline: 1.1985x; 1.1985x over previous
//
#include <hip/hip_runtime.h>
#include <math.h>

#define B_   256
#define IN_  512
#define C_   4
#define M_   6
#define K_   64
#define S1_  255
#define S2_  63

#define NBLK1 (C_ * S1_)                 // 1020
#define NBLK2 (C_ * S2_)                 // 252
#define NBLK3 (C_)                       // 4
#define NBLK_ALL (NBLK1 + NBLK2 + NBLK3) // 1276

#define LMIN_ (-6.906754778648554f)
#define LMAX_ ( 6.906754778648554f)
#define LR_   0.001f
#define WCLIP_ 5.0f

__device__ __forceinline__ float clampf(float v, float lo, float hi) {
    return fminf(fmaxf(v, lo), hi);
}

// One-time prep: l0[b][i]; bias columns of out1RM/out2RM. Pure elementwise.
__global__ __launch_bounds__(256) void prep_kernel(const float* __restrict__ x,
                                                   const float* __restrict__ bias1,
                                                   const float* __restrict__ bias2,
                                                   float* __restrict__ l0,
                                                   float* __restrict__ out1RM,
                                                   float* __restrict__ out2RM) {
    int gid = blockIdx.x * 256 + threadIdx.x;     // 0..131071
    float xv = x[gid];
    float xc = clampf(xv, 0.001f, 0.999f);
    int i = gid & (IN_ - 1);
    l0[gid] = (i == 0) ? 0.0f : logf(xc / (1.0f - xc));
    if (gid < C_ * B_) {
        int c = gid >> 8, b = gid & 255;
        out1RM[((size_t)c * B_ + b) * (S1_ + 1)] = bias1[c];
        out2RM[((size_t)c * B_ + b) * (S2_ + 1)] = bias2[c];
    }
}

// Routing: 512 threads = 2 tiles; wave-uniform tile select (readfirstlane ->
// cmaps stays in s_loads). Thread = batch b, full-k sequential 6-acc dot.
// No LDS, no barriers. k-order identical to rounds 1-6.
__global__ __launch_bounds__(512) void route_kernel(
    const float* __restrict__ x,        // [B][IN] raw context, row-major
    const float* __restrict__ cmaps1,
    const float* __restrict__ cmaps2,
    const float* __restrict__ cmaps3,
    int* __restrict__ idx_buf)          // [NBLK_ALL][B]
{
    const int tid = threadIdx.x;
    const int u   = __builtin_amdgcn_readfirstlane(tid >> 8);  // wave-uniform
    const int b   = tid & 255;
    const int bid = blockIdx.x * 2 + u;

    const float* cmp;
    if (bid < NBLK1)              cmp = cmaps1 + (size_t)bid * M_ * IN_;
    else if (bid < NBLK1 + NBLK2) cmp = cmaps2 + (size_t)(bid - NBLK1) * M_ * IN_;
    else                          cmp = cmaps3 + (size_t)(bid - NBLK1 - NBLK2) * M_ * IN_;

    const float* xr = x + (size_t)b * IN_;
    float acc[M_];
#pragma unroll
    for (int m = 0; m < M_; ++m) acc[m] = 0.0f;

    for (int k0 = 0; k0 < IN_; k0 += 32) {
        float4 xv[8];
#pragma unroll
        for (int j = 0; j < 8; ++j) xv[j] = *(const float4*)(xr + k0 + 4 * j);
#pragma unroll
        for (int j = 0; j < 8; ++j) {
            const float xs[4] = {xv[j].x, xv[j].y, xv[j].z, xv[j].w};
#pragma unroll
            for (int t = 0; t < 4; ++t)
#pragma unroll
                for (int m = 0; m < M_; ++m)
                    acc[m] = fmaf(cmp[(size_t)m * IN_ + k0 + 4 * j + t], xs[t], acc[m]);
        }
    }
    int myidx = 0;
#pragma unroll
    for (int m = 0; m < M_; ++m) myidx |= (acc[m] > 0.0f) ? (1 << m) : 0;
    idx_buf[(size_t)bid * B_ + b] = myidx;
}

// Partial dot: block = (tile, 64-wide k-slice). lg segment in registers,
// w slice in LDS (pad 68 -> 16B-aligned float4 gather). One barrier.
template<int DIN, int KSPL>
__global__ __launch_bounds__(256) void dot_kernel(
    const float* __restrict__ lgRM, long lg_sc,
    const float* __restrict__ w,
    const int* __restrict__ idx_buf,
    float* __restrict__ pdot,          // [tiles][KSPL][B]
    int S)
{
    constexpr int KR  = DIN / KSPL;    // = 64
    static_assert(KR == 64, "k-slice must be 64");
    constexpr int PAD = 68;            // 68*4 = 272 B row pitch, 16B-aligned
    __shared__ float wl[K_ * PAD];

    const int bid  = blockIdx.x;
    const int tile = bid / KSPL;
    const int ks   = bid % KSPL;
    const int c    = tile / S;
    const int tid  = threadIdx.x;
    const int b    = tid;
    const int k0   = ks * KR;

    const int myrow = idx_buf[(size_t)tile * B_ + b];

    // lg row segment -> 16 float4 regs (per-lane contiguous)
    const float* lgr = lgRM + (size_t)c * lg_sc + (size_t)b * DIN + k0;
    float4 lgv[16];
#pragma unroll
    for (int j = 0; j < 16; ++j) lgv[j] = *(const float4*)(lgr + 4 * j);

    // stage w 64x64 slice (coalesced f4), 4 per thread
    const float* wp = w + (size_t)tile * K_ * DIN + k0;
#pragma unroll
    for (int j = 0; j < 4; ++j) {
        int f   = tid + 256 * j;
        int row = f >> 4;
        int q   = (f & 15) << 2;
        float4 v = *(const float4*)(wp + (size_t)row * DIN + q);
        *(float4*)(wl + row * PAD + q) = v;
    }
    __syncthreads();

    const float4* wr = (const float4*)(wl + myrow * PAD);
    float dot = 0.0f;
#pragma unroll
    for (int j = 0; j < 16; ++j) {
        float4 wv = wr[j];
        dot = fmaf(wv.x, lgv[j].x, dot);
        dot = fmaf(wv.y, lgv[j].y, dot);
        dot = fmaf(wv.z, lgv[j].z, dot);
        dot = fmaf(wv.w, lgv[j].w, dot);
    }
    pdot[((size_t)tile * KSPL + ks) * B_ + b] = dot;
}

// Finalize: sum partials (fixed order), clip, outputs, diff, winner, dw.
__global__ __launch_bounds__(256) void fin_kernel(
    const float* __restrict__ pdot, int KSPL,
    const int* __restrict__ idx_buf,
    const int* __restrict__ target,
    float* __restrict__ onextRM,       // [c][b][S+1] or logits[b][C]
    int* __restrict__ win_g,           // [tiles][K]
    float* __restrict__ dw_g,          // [tiles][K]
    int S, int is_last)
{
    __shared__ float diff_s[B_];
    __shared__ int   win_s[K_];
    const int tile = blockIdx.x;
    const int c    = tile / S;
    const int s    = tile - c * S;
    const int b    = threadIdx.x;

    if (b < K_) win_s[b] = -1;

    float dot = 0.0f;
    for (int j = 0; j < KSPL; ++j)
        dot += pdot[((size_t)tile * KSPL + j) * B_ + b];

    float outv = clampf(dot, LMIN_, LMAX_);
    if (is_last) onextRM[(size_t)b * C_ + c] = outv;
    else         onextRM[((size_t)c * B_ + b) * (size_t)(S + 1) + (s + 1)] = outv;

    float tg = (target[b] == c) ? 1.0f : 0.0f;
    diff_s[b] = 1.0f / (1.0f + expf(-outv)) - tg;
    const int myrow = idx_buf[(size_t)tile * B_ + b];
    __syncthreads();
    atomicMax(&win_s[myrow], b);         // last-b-wins == max b
    __syncthreads();
    if (b < K_) {
        int bw = win_s[b];
        win_g[(size_t)tile * K_ + b] = bw;
        dw_g[(size_t)tile * K_ + b]  = (bw >= 0) ? LR_ * diff_s[bw] : 0.0f;
    }
}

// Stream update: thread -> 8 float4.
template<int DIN>
__global__ __launch_bounds__(256) void update_kernel(
    const float* __restrict__ w,
    const float* __restrict__ lgRM, long lg_sc,
    const int* __restrict__ win_g,
    const float* __restrict__ dw_g,
    float* __restrict__ nw,
    int SK)                            // S * K_ (rows per class)
{
    constexpr int QPR = DIN / 4;
    constexpr int QSH = (DIN == 512) ? 7 : (DIN == 256) ? 6 : 4;
    const int base = blockIdx.x * 2048 + threadIdx.x;
#pragma unroll
    for (int j = 0; j < 8; ++j) {
        int Q   = base + j * 256;
        int row = Q >> QSH;
        int col = (Q & (QPR - 1)) << 2;
        float4 wv = *(const float4*)(w + (size_t)row * DIN + col);
        int bw = win_g[row];
        if (bw >= 0) {
            float d = dw_g[row];
            int cc  = row / SK;
            const float4 lv = *(const float4*)(lgRM + (size_t)cc * lg_sc + (size_t)bw * DIN + col);
            wv.x = clampf(wv.x - d * lv.x, -WCLIP_, WCLIP_);
            wv.y = clampf(wv.y - d * lv.y, -WCLIP_, WCLIP_);
            wv.z = clampf(wv.z - d * lv.z, -WCLIP_, WCLIP_);
            wv.w = clampf(wv.w - d * lv.w, -WCLIP_, WCLIP_);
        }
        *(float4*)(nw + (size_t)row * DIN + col) = wv;
    }
}

extern "C" void kernel_launch(void* const* d_in, const int* in_sizes, int n_in,
                              void* d_out, int out_size, void* d_ws, size_t ws_size,
                              hipStream_t stream) {
    const float* x      = (const float*)d_in[0];
    const int*   target = (const int*)  d_in[1];
    const float* cmaps1 = (const float*)d_in[2];
    const float* w1     = (const float*)d_in[3];
    const float* bias1  = (const float*)d_in[4];
    const float* cmaps2 = (const float*)d_in[5];
    const float* w2     = (const float*)d_in[6];
    const float* bias2  = (const float*)d_in[7];
    const float* cmaps3 = (const float*)d_in[8];
    const float* w3     = (const float*)d_in[9];
    float* out = (float*)d_out;

    float* l0      = (float*)d_ws;                           // 131072
    float* out1RM  = l0     + (size_t)B_ * IN_;              // 262144
    float* out2RM  = out1RM + (size_t)C_ * B_ * (S1_ + 1);   // 65536
    float* pdot    = out2RM + (size_t)C_ * B_ * (S2_ + 1);   // NBLK1*8*B
    float* dw_g    = pdot   + (size_t)NBLK1 * 8 * B_;        // NBLK_ALL*K
    int*   win_g   = (int*)(dw_g + (size_t)NBLK_ALL * K_);   // NBLK_ALL*K
    int*   idx_buf = (int*)(win_g + (size_t)NBLK_ALL * K_);  // NBLK_ALL*B

    float* logits = out;
    float* nw1 = out + (size_t)B_ * C_;
    float* nw2 = nw1 + (size_t)C_ * S1_ * K_ * IN_;
    float* nw3 = nw2 + (size_t)C_ * S2_ * K_ * (S1_ + 1);

    prep_kernel<<<dim3(512), dim3(256), 0, stream>>>(
        x, bias1, bias2, l0, out1RM, out2RM);

    route_kernel<<<dim3(NBLK_ALL / 2), dim3(512), 0, stream>>>(
        x, cmaps1, cmaps2, cmaps3, idx_buf);

    const int* idx1 = idx_buf;
    const int* idx2 = idx_buf + (size_t)NBLK1 * B_;
    const int* idx3 = idx_buf + (size_t)(NBLK1 + NBLK2) * B_;
    int*   win1 = win_g;                         float* dw1 = dw_g;
    int*   win2 = win_g + NBLK1 * K_;            float* dw2 = dw_g + NBLK1 * K_;
    int*   win3 = win_g + (NBLK1 + NBLK2) * K_;  float* dw3 = dw_g + (NBLK1 + NBLK2) * K_;

    // ---- layer 1 (DIN=512, lg = l0, c-stride 0) ----
    dot_kernel<512, 8><<<dim3(NBLK1 * 8), dim3(256), 0, stream>>>(
        l0, 0L, w1, idx1, pdot, S1_);
    fin_kernel<<<dim3(NBLK1), dim3(256), 0, stream>>>(
        pdot, 8, idx1, target, out1RM, win1, dw1, S1_, 0);
    update_kernel<512><<<dim3(NBLK1 * K_ * 128 / 2048), dim3(256), 0, stream>>>(
        w1, l0, 0L, win1, dw1, nw1, S1_ * K_);

    // ---- layer 2 (DIN=256, lg = out1RM) ----
    dot_kernel<256, 4><<<dim3(NBLK2 * 4), dim3(256), 0, stream>>>(
        out1RM, (long)B_ * (S1_ + 1), w2, idx2, pdot, S2_);
    fin_kernel<<<dim3(NBLK2), dim3(256), 0, stream>>>(
        pdot, 4, idx2, target, out2RM, win2, dw2, S2_, 0);
    update_kernel<256><<<dim3(NBLK2 * K_ * 64 / 2048), dim3(256), 0, stream>>>(
        w2, out1RM, (long)B_ * (S1_ + 1), win2, dw2, nw2, S2_ * K_);

    // ---- layer 3 (DIN=64, lg = out2RM) ----
    dot_kernel<64, 1><<<dim3(NBLK3), dim3(256), 0, stream>>>(
        out2RM, (long)B_ * (S2_ + 1), w3, idx3, pdot, 1);
    fin_kernel<<<dim3(NBLK3), dim3(256), 0, stream>>>(
        pdot, 1, idx3, target, logits, win3, dw3, 1, 1);
    update_kernel<64><<<dim3(NBLK3 * K_ * 16 / 2048), dim3(256), 0, stream>>>(
        w3, out2RM, (long)B_ * (S2_ + 1), win3, dw3, nw3, K_);
}

// Round 9
// 154.537 us; speedup vs baseline: 2.1960x; 1.8323x over previous
//
#include <hip/hip_runtime.h>
#include <math.h>

#define B_   256
#define IN_  512
#define C_   4
#define M_   6
#define K_   64
#define S1_  255
#define S2_  63

#define NBLK1 (C_ * S1_)                 // 1020
#define NBLK2 (C_ * S2_)                 // 252
#define NBLK3 (C_)                       // 4
#define NBLK_ALL (NBLK1 + NBLK2 + NBLK3) // 1276

#define LMIN_ (-6.906754778648554f)
#define LMAX_ ( 6.906754778648554f)
#define LR_   0.001f
#define WCLIP_ 5.0f

__device__ __forceinline__ float clampf(float v, float lo, float hi) {
    return fminf(fmaxf(v, lo), hi);
}

// One-time prep: xT[i][b], l0[b][i], l0T[i][b]; bias rows of out1/out2.
__global__ __launch_bounds__(256) void prep_kernel(const float* __restrict__ x,
                                                   const float* __restrict__ bias1,
                                                   const float* __restrict__ bias2,
                                                   float* __restrict__ xT,
                                                   float* __restrict__ l0,
                                                   float* __restrict__ l0T,
                                                   float* __restrict__ out1T,
                                                   float* __restrict__ out1RM,
                                                   float* __restrict__ out2T,
                                                   float* __restrict__ out2RM) {
    __shared__ float tx_[32][33];
    __shared__ float tl_[32][33];
    const int i0 = (blockIdx.x & 15) * 32;
    const int b0 = (blockIdx.x >> 4) * 32;
    const int tx = threadIdx.x & 31;
    const int ty = threadIdx.x >> 5;
#pragma unroll
    for (int r = 0; r < 4; ++r) {
        int bb = b0 + ty + 8 * r;
        int ii = i0 + tx;
        float xv = x[(size_t)bb * IN_ + ii];
        float xc = clampf(xv, 0.001f, 0.999f);
        float lv = (ii == 0) ? 0.0f : logf(xc / (1.0f - xc));
        l0[(size_t)bb * IN_ + ii] = lv;
        tx_[ty + 8 * r][tx] = xv;
        tl_[ty + 8 * r][tx] = lv;
    }
    __syncthreads();
#pragma unroll
    for (int r = 0; r < 4; ++r) {
        int ii = i0 + ty + 8 * r;
        int bb = b0 + tx;
        xT[(size_t)ii * B_ + bb]  = tx_[tx][ty + 8 * r];
        l0T[(size_t)ii * B_ + bb] = tl_[tx][ty + 8 * r];
    }
    int gid = blockIdx.x * 256 + threadIdx.x;
    if (gid < C_ * B_) {
        int c = gid >> 8, b = gid & 255;
        float b1 = bias1[c], b2 = bias2[c];
        out1T[((size_t)c * (S1_ + 1)) * B_ + b] = b1;
        out1RM[((size_t)c * B_ + b) * (S1_ + 1)] = b1;
        out2T[((size_t)c * (S2_ + 1)) * B_ + b] = b2;
        out2RM[((size_t)c * B_ + b) * (S2_ + 1)] = b2;
    }
}

// Routing: block = tile, 4 waves split k into 128-wide quarters.
// cmaps via wave-uniform s_loads; xT coalesced; LDS combine in fixed order.
__global__ __launch_bounds__(256) void route_kernel(
    const float* __restrict__ xT,       // [IN][B]
    const float* __restrict__ cmaps1,
    const float* __restrict__ cmaps2,
    const float* __restrict__ cmaps3,
    int* __restrict__ idx_buf)          // [NBLK_ALL][B]
{
    __shared__ float sacc[3][M_][B_];   // 18 KB
    const int bid  = blockIdx.x;
    const int wv   = __builtin_amdgcn_readfirstlane(threadIdx.x >> 6); // wave-uniform
    const int lane = threadIdx.x & 63;

    const float* cmp;
    if (bid < NBLK1)              cmp = cmaps1 + (size_t)bid * M_ * IN_;
    else if (bid < NBLK1 + NBLK2) cmp = cmaps2 + (size_t)(bid - NBLK1) * M_ * IN_;
    else                          cmp = cmaps3 + (size_t)(bid - NBLK1 - NBLK2) * M_ * IN_;

    float acc[4][M_];                   // b = 64*jb + lane
#pragma unroll
    for (int jb = 0; jb < 4; ++jb)
#pragma unroll
        for (int m = 0; m < M_; ++m) acc[jb][m] = 0.0f;

    const int kw = wv * 128;
    for (int k0 = kw; k0 < kw + 128; k0 += 8) {
        float xv[8][4];
#pragma unroll
        for (int j = 0; j < 8; ++j)
#pragma unroll
            for (int jb = 0; jb < 4; ++jb)
                xv[j][jb] = xT[(size_t)(k0 + j) * B_ + 64 * jb + lane];  // coalesced
#pragma unroll
        for (int j = 0; j < 8; ++j)
#pragma unroll
            for (int m = 0; m < M_; ++m) {
                float cv = cmp[(size_t)m * IN_ + k0 + j];                // s_load
#pragma unroll
                for (int jb = 0; jb < 4; ++jb)
                    acc[jb][m] = fmaf(cv, xv[j][jb], acc[jb][m]);
            }
    }

    if (wv > 0) {
#pragma unroll
        for (int jb = 0; jb < 4; ++jb)
#pragma unroll
            for (int m = 0; m < M_; ++m)
                sacc[wv - 1][m][64 * jb + lane] = acc[jb][m];
    }
    __syncthreads();
    if (wv == 0) {
#pragma unroll
        for (int jb = 0; jb < 4; ++jb) {
            int b = 64 * jb + lane;
            int myidx = 0;
#pragma unroll
            for (int m = 0; m < M_; ++m) {
                float t = acc[jb][m] + sacc[0][m][b] + sacc[1][m][b] + sacc[2][m][b];
                myidx |= (t > 0.0f) ? (1 << m) : 0;
            }
            idx_buf[(size_t)bid * B_ + b] = myidx;
        }
    }
}

// Partial dot: block = (tile, 64-wide k-slice). w slice in LDS pitch-65
// (conflict-free scalar gather); lgT coalesced. One barrier.
template<int DIN, int KSPL>
__global__ __launch_bounds__(256) void dot_kernel(
    const float* __restrict__ lgT, long lgT_sc,   // lgT[c*sc + k*B + b]
    const float* __restrict__ w,
    const int* __restrict__ idx_buf,
    float* __restrict__ pdot,          // [tiles][KSPL][B]
    int S)
{
    constexpr int KR  = DIN / KSPL;    // = 64
    static_assert(KR == 64, "k-slice must be 64");
    constexpr int PAD = 65;
    __shared__ float wl[K_ * PAD];     // 16.25 KB

    const int bid  = blockIdx.x;
    const int tile = bid / KSPL;
    const int ks   = bid % KSPL;
    const int c    = tile / S;
    const int tid  = threadIdx.x;
    const int b    = tid;
    const int k0   = ks * KR;

    const int myrow = idx_buf[(size_t)tile * B_ + b];

    // stage w 64x64 slice: coalesced f4 global loads, scalar LDS writes
    const float* wp = w + (size_t)tile * K_ * DIN + k0;
#pragma unroll
    for (int j = 0; j < 4; ++j) {
        int f   = tid + 256 * j;
        int row = f >> 4;
        int q   = (f & 15) << 2;
        float4 v = *(const float4*)(wp + (size_t)row * DIN + q);
        wl[row * PAD + q + 0] = v.x;
        wl[row * PAD + q + 1] = v.y;
        wl[row * PAD + q + 2] = v.z;
        wl[row * PAD + q + 3] = v.w;
    }
    __syncthreads();

    const float* lgp = lgT + (size_t)c * lgT_sc + (size_t)k0 * B_ + b;
    const float* wr  = wl + myrow * PAD;
    float dot = 0.0f;
    for (int kk = 0; kk < KR; kk += 8) {
        float lv[8];
#pragma unroll
        for (int t = 0; t < 8; ++t) lv[t] = lgp[(size_t)(kk + t) * B_];  // coalesced
#pragma unroll
        for (int t = 0; t < 8; ++t) dot = fmaf(wr[kk + t], lv[t], dot);  // broadcast/2-way
    }
    pdot[((size_t)tile * KSPL + ks) * B_ + b] = dot;
}

// Finalize: sum partials (fixed order), clip, outputs (both layouts),
// diff, winner, per-row dw.
__global__ __launch_bounds__(256) void fin_kernel(
    const float* __restrict__ pdot, int KSPL,
    const int* __restrict__ idx_buf,
    const int* __restrict__ target,
    float* __restrict__ onextT,        // [c][S+1][b] (null if last)
    float* __restrict__ onextRM,       // [c][b][S+1] or logits[b][C]
    int* __restrict__ win_g,           // [tiles][K]
    float* __restrict__ dw_g,          // [tiles][K]
    int S, int is_last)
{
    __shared__ float diff_s[B_];
    __shared__ int   win_s[K_];
    const int tile = blockIdx.x;
    const int c    = tile / S;
    const int s    = tile - c * S;
    const int b    = threadIdx.x;

    if (b < K_) win_s[b] = -1;

    float dot = 0.0f;
    for (int j = 0; j < KSPL; ++j)
        dot += pdot[((size_t)tile * KSPL + j) * B_ + b];

    float outv = clampf(dot, LMIN_, LMAX_);
    if (is_last) {
        onextRM[(size_t)b * C_ + c] = outv;
    } else {
        onextT[((size_t)c * (S + 1) + (s + 1)) * B_ + b] = outv;   // coalesced
        onextRM[((size_t)c * B_ + b) * (size_t)(S + 1) + (s + 1)] = outv;
    }
    float tg = (target[b] == c) ? 1.0f : 0.0f;
    diff_s[b] = 1.0f / (1.0f + expf(-outv)) - tg;
    const int myrow = idx_buf[(size_t)tile * B_ + b];
    __syncthreads();
    atomicMax(&win_s[myrow], b);         // last-b-wins == max b
    __syncthreads();
    if (b < K_) {
        int bw = win_s[b];
        win_g[(size_t)tile * K_ + b] = bw;
        dw_g[(size_t)tile * K_ + b]  = (bw >= 0) ? LR_ * diff_s[bw] : 0.0f;
    }
}

// Stream update: thread -> 8 float4.
template<int DIN>
__global__ __launch_bounds__(256) void update_kernel(
    const float* __restrict__ w,
    const float* __restrict__ lgRM, long lg_sc,
    const int* __restrict__ win_g,
    const float* __restrict__ dw_g,
    float* __restrict__ nw,
    int SK)                            // S * K_ (rows per class)
{
    constexpr int QPR = DIN / 4;
    constexpr int QSH = (DIN == 512) ? 7 : (DIN == 256) ? 6 : 4;
    const int base = blockIdx.x * 2048 + threadIdx.x;
#pragma unroll
    for (int j = 0; j < 8; ++j) {
        int Q   = base + j * 256;
        int row = Q >> QSH;
        int col = (Q & (QPR - 1)) << 2;
        float4 wv = *(const float4*)(w + (size_t)row * DIN + col);
        int bw = win_g[row];
        if (bw >= 0) {
            float d = dw_g[row];
            int cc  = row / SK;
            const float4 lv = *(const float4*)(lgRM + (size_t)cc * lg_sc + (size_t)bw * DIN + col);
            wv.x = clampf(wv.x - d * lv.x, -WCLIP_, WCLIP_);
            wv.y = clampf(wv.y - d * lv.y, -WCLIP_, WCLIP_);
            wv.z = clampf(wv.z - d * lv.z, -WCLIP_, WCLIP_);
            wv.w = clampf(wv.w - d * lv.w, -WCLIP_, WCLIP_);
        }
        *(float4*)(nw + (size_t)row * DIN + col) = wv;
    }
}

extern "C" void kernel_launch(void* const* d_in, const int* in_sizes, int n_in,
                              void* d_out, int out_size, void* d_ws, size_t ws_size,
                              hipStream_t stream) {
    const float* x      = (const float*)d_in[0];
    const int*   target = (const int*)  d_in[1];
    const float* cmaps1 = (const float*)d_in[2];
    const float* w1     = (const float*)d_in[3];
    const float* bias1  = (const float*)d_in[4];
    const float* cmaps2 = (const float*)d_in[5];
    const float* w2     = (const float*)d_in[6];
    const float* bias2  = (const float*)d_in[7];
    const float* cmaps3 = (const float*)d_in[8];
    const float* w3     = (const float*)d_in[9];
    float* out = (float*)d_out;

    float* xT      = (float*)d_ws;                           // 131072
    float* l0      = xT     + (size_t)IN_ * B_;              // 131072
    float* l0T     = l0     + (size_t)B_ * IN_;              // 131072
    float* out1T   = l0T    + (size_t)IN_ * B_;              // 262144
    float* out1RM  = out1T  + (size_t)C_ * (S1_ + 1) * B_;   // 262144
    float* out2T   = out1RM + (size_t)C_ * B_ * (S1_ + 1);   // 65536
    float* out2RM  = out2T  + (size_t)C_ * (S2_ + 1) * B_;   // 65536
    float* pdot    = out2RM + (size_t)C_ * B_ * (S2_ + 1);   // NBLK1*8*B
    float* dw_g    = pdot   + (size_t)NBLK1 * 8 * B_;        // NBLK_ALL*K
    int*   win_g   = (int*)(dw_g + (size_t)NBLK_ALL * K_);   // NBLK_ALL*K
    int*   idx_buf = (int*)(win_g + (size_t)NBLK_ALL * K_);  // NBLK_ALL*B

    float* logits = out;
    float* nw1 = out + (size_t)B_ * C_;
    float* nw2 = nw1 + (size_t)C_ * S1_ * K_ * IN_;
    float* nw3 = nw2 + (size_t)C_ * S2_ * K_ * (S1_ + 1);

    prep_kernel<<<dim3(128), dim3(256), 0, stream>>>(
        x, bias1, bias2, xT, l0, l0T, out1T, out1RM, out2T, out2RM);

    route_kernel<<<dim3(NBLK_ALL), dim3(256), 0, stream>>>(
        xT, cmaps1, cmaps2, cmaps3, idx_buf);

    const int* idx1 = idx_buf;
    const int* idx2 = idx_buf + (size_t)NBLK1 * B_;
    const int* idx3 = idx_buf + (size_t)(NBLK1 + NBLK2) * B_;
    int*   win1 = win_g;                         float* dw1 = dw_g;
    int*   win2 = win_g + NBLK1 * K_;            float* dw2 = dw_g + NBLK1 * K_;
    int*   win3 = win_g + (NBLK1 + NBLK2) * K_;  float* dw3 = dw_g + (NBLK1 + NBLK2) * K_;

    // ---- layer 1 (DIN=512, lg = l0/l0T, c-stride 0) ----
    dot_kernel<512, 8><<<dim3(NBLK1 * 8), dim3(256), 0, stream>>>(
        l0T, 0L, w1, idx1, pdot, S1_);
    fin_kernel<<<dim3(NBLK1), dim3(256), 0, stream>>>(
        pdot, 8, idx1, target, out1T, out1RM, win1, dw1, S1_, 0);
    update_kernel<512><<<dim3(NBLK1 * K_ * 128 / 2048), dim3(256), 0, stream>>>(
        w1, l0, 0L, win1, dw1, nw1, S1_ * K_);

    // ---- layer 2 (DIN=256, lg = out1) ----
    dot_kernel<256, 4><<<dim3(NBLK2 * 4), dim3(256), 0, stream>>>(
        out1T, (long)(S1_ + 1) * B_, w2, idx2, pdot, S2_);
    fin_kernel<<<dim3(NBLK2), dim3(256), 0, stream>>>(
        pdot, 4, idx2, target, out2T, out2RM, win2, dw2, S2_, 0);
    update_kernel<256><<<dim3(NBLK2 * K_ * 64 / 2048), dim3(256), 0, stream>>>(
        w2, out1RM, (long)B_ * (S1_ + 1), win2, dw2, nw2, S2_ * K_);

    // ---- layer 3 (DIN=64, lg = out2) ----
    dot_kernel<64, 1><<<dim3(NBLK3), dim3(256), 0, stream>>>(
        out2T, (long)(S2_ + 1) * B_, w3, idx3, pdot, 1);
    fin_kernel<<<dim3(NBLK3), dim3(256), 0, stream>>>(
        pdot, 1, idx3, target, nullptr, logits, win3, dw3, 1, 1);
    update_kernel<64><<<dim3(NBLK3 * K_ * 16 / 2048), dim3(256), 0, stream>>>(
        w3, out2RM, (long)B_ * (S2_ + 1), win3, dw3, nw3, K_);
}

// Round 10
// 140.158 us; speedup vs baseline: 2.4213x; 1.1026x over previous
//
#include <hip/hip_runtime.h>
#include <math.h>

#define B_   256
#define IN_  512
#define C_   4
#define M_   6
#define K_   64
#define S1_  255
#define S2_  63

#define NBLK1 (C_ * S1_)                 // 1020
#define NBLK2 (C_ * S2_)                 // 252
#define NBLK3 (C_)                       // 4
#define NBLK_ALL (NBLK1 + NBLK2 + NBLK3) // 1276

#define LMIN_ (-6.906754778648554f)
#define LMAX_ ( 6.906754778648554f)
#define LR_   0.001f
#define WCLIP_ 5.0f

typedef float v4f __attribute__((ext_vector_type(4)));

__device__ __forceinline__ float clampf(float v, float lo, float hi) {
    return fminf(fmaxf(v, lo), hi);
}

// One-time prep: xT[i][b], l0[b][i], l0T[i][b]; bias rows of out1/out2.
__global__ __launch_bounds__(256) void prep_kernel(const float* __restrict__ x,
                                                   const float* __restrict__ bias1,
                                                   const float* __restrict__ bias2,
                                                   float* __restrict__ xT,
                                                   float* __restrict__ l0,
                                                   float* __restrict__ l0T,
                                                   float* __restrict__ out1T,
                                                   float* __restrict__ out1RM,
                                                   float* __restrict__ out2T,
                                                   float* __restrict__ out2RM) {
    __shared__ float tx_[32][33];
    __shared__ float tl_[32][33];
    const int i0 = (blockIdx.x & 15) * 32;
    const int b0 = (blockIdx.x >> 4) * 32;
    const int tx = threadIdx.x & 31;
    const int ty = threadIdx.x >> 5;
#pragma unroll
    for (int r = 0; r < 4; ++r) {
        int bb = b0 + ty + 8 * r;
        int ii = i0 + tx;
        float xv = x[(size_t)bb * IN_ + ii];
        float xc = clampf(xv, 0.001f, 0.999f);
        float lv = (ii == 0) ? 0.0f : logf(xc / (1.0f - xc));
        l0[(size_t)bb * IN_ + ii] = lv;
        tx_[ty + 8 * r][tx] = xv;
        tl_[ty + 8 * r][tx] = lv;
    }
    __syncthreads();
#pragma unroll
    for (int r = 0; r < 4; ++r) {
        int ii = i0 + ty + 8 * r;
        int bb = b0 + tx;
        xT[(size_t)ii * B_ + bb]  = tx_[tx][ty + 8 * r];
        l0T[(size_t)ii * B_ + bb] = tl_[tx][ty + 8 * r];
    }
    int gid = blockIdx.x * 256 + threadIdx.x;
    if (gid < C_ * B_) {
        int c = gid >> 8, b = gid & 255;
        float b1 = bias1[c], b2 = bias2[c];
        out1T[((size_t)c * (S1_ + 1)) * B_ + b] = b1;
        out1RM[((size_t)c * B_ + b) * (S1_ + 1)] = b1;
        out2T[((size_t)c * (S2_ + 1)) * B_ + b] = b2;
        out2RM[((size_t)c * B_ + b) * (S2_ + 1)] = b2;
    }
}

// Routing: block = tile, 4 waves split k into 128-wide quarters.
// cmaps via wave-uniform s_loads; xT coalesced; LDS combine in fixed order.
__global__ __launch_bounds__(256) void route_kernel(
    const float* __restrict__ xT,       // [IN][B]
    const float* __restrict__ cmaps1,
    const float* __restrict__ cmaps2,
    const float* __restrict__ cmaps3,
    int* __restrict__ idx_buf)          // [NBLK_ALL][B]
{
    __shared__ float sacc[3][M_][B_];   // 18 KB
    const int bid  = blockIdx.x;
    const int wv   = __builtin_amdgcn_readfirstlane(threadIdx.x >> 6); // wave-uniform
    const int lane = threadIdx.x & 63;

    const float* cmp;
    if (bid < NBLK1)              cmp = cmaps1 + (size_t)bid * M_ * IN_;
    else if (bid < NBLK1 + NBLK2) cmp = cmaps2 + (size_t)(bid - NBLK1) * M_ * IN_;
    else                          cmp = cmaps3 + (size_t)(bid - NBLK1 - NBLK2) * M_ * IN_;

    float acc[4][M_];                   // b = 64*jb + lane
#pragma unroll
    for (int jb = 0; jb < 4; ++jb)
#pragma unroll
        for (int m = 0; m < M_; ++m) acc[jb][m] = 0.0f;

    const int kw = wv * 128;
    for (int k0 = kw; k0 < kw + 128; k0 += 8) {
        float xv[8][4];
#pragma unroll
        for (int j = 0; j < 8; ++j)
#pragma unroll
            for (int jb = 0; jb < 4; ++jb)
                xv[j][jb] = xT[(size_t)(k0 + j) * B_ + 64 * jb + lane];  // coalesced
#pragma unroll
        for (int j = 0; j < 8; ++j)
#pragma unroll
            for (int m = 0; m < M_; ++m) {
                float cv = cmp[(size_t)m * IN_ + k0 + j];                // s_load
#pragma unroll
                for (int jb = 0; jb < 4; ++jb)
                    acc[jb][m] = fmaf(cv, xv[j][jb], acc[jb][m]);
            }
    }

    if (wv > 0) {
#pragma unroll
        for (int jb = 0; jb < 4; ++jb)
#pragma unroll
            for (int m = 0; m < M_; ++m)
                sacc[wv - 1][m][64 * jb + lane] = acc[jb][m];
    }
    __syncthreads();
    if (wv == 0) {
#pragma unroll
        for (int jb = 0; jb < 4; ++jb) {
            int b = 64 * jb + lane;
            int myidx = 0;
#pragma unroll
            for (int m = 0; m < M_; ++m) {
                float t = acc[jb][m] + sacc[0][m][b] + sacc[1][m][b] + sacc[2][m][b];
                myidx |= (t > 0.0f) ? (1 << m) : 0;
            }
            idx_buf[(size_t)bid * B_ + b] = myidx;
        }
    }
}

// Partial dot: block = (tile, 64-wide k-slice). w slice in LDS pitch-65
// (conflict-free scalar gather); lgT coalesced. One barrier.
template<int DIN, int KSPL>
__global__ __launch_bounds__(256) void dot_kernel(
    const float* __restrict__ lgT, long lgT_sc,   // lgT[c*sc + k*B + b]
    const float* __restrict__ w,
    const int* __restrict__ idx_buf,
    float* __restrict__ pdot,          // [tiles][KSPL][B]
    int S)
{
    constexpr int KR  = DIN / KSPL;    // = 64
    static_assert(KR == 64, "k-slice must be 64");
    constexpr int PAD = 65;
    __shared__ float wl[K_ * PAD];     // 16.25 KB

    const int bid  = blockIdx.x;
    const int tile = bid / KSPL;
    const int ks   = bid % KSPL;
    const int c    = tile / S;
    const int tid  = threadIdx.x;
    const int b    = tid;
    const int k0   = ks * KR;

    const int myrow = idx_buf[(size_t)tile * B_ + b];

    // stage w 64x64 slice: coalesced f4 global loads, scalar LDS writes
    const float* wp = w + (size_t)tile * K_ * DIN + k0;
#pragma unroll
    for (int j = 0; j < 4; ++j) {
        int f   = tid + 256 * j;
        int row = f >> 4;
        int q   = (f & 15) << 2;
        float4 v = *(const float4*)(wp + (size_t)row * DIN + q);
        wl[row * PAD + q + 0] = v.x;
        wl[row * PAD + q + 1] = v.y;
        wl[row * PAD + q + 2] = v.z;
        wl[row * PAD + q + 3] = v.w;
    }
    __syncthreads();

    const float* lgp = lgT + (size_t)c * lgT_sc + (size_t)k0 * B_ + b;
    const float* wr  = wl + myrow * PAD;
    float dot = 0.0f;
    for (int kk = 0; kk < KR; kk += 8) {
        float lv[8];
#pragma unroll
        for (int t = 0; t < 8; ++t) lv[t] = lgp[(size_t)(kk + t) * B_];  // coalesced
#pragma unroll
        for (int t = 0; t < 8; ++t) dot = fmaf(wr[kk + t], lv[t], dot);  // broadcast/2-way
    }
    pdot[((size_t)tile * KSPL + ks) * B_ + b] = dot;
}

// Fused fin + update. Blocks [0, ntiles): fin (output writes only).
// Blocks [ntiles, ntiles*(1+UPB)): update; each inline-recomputes winner/dw
// from pdot (block-local: 256 threads == all b), streams K_/UPB rows.
template<int DIN, int KSPL, int UPB>
__global__ __launch_bounds__(256) void finup_kernel(
    const float* __restrict__ pdot,    // [tiles][KSPL][B]
    const int* __restrict__ idx_buf,   // [tiles][B]
    const int* __restrict__ target,
    const float* __restrict__ lgRM, long lg_sc,
    const float* __restrict__ w,
    float* __restrict__ nw,
    float* __restrict__ onextT,        // [c][S+1][b] (null if last)
    float* __restrict__ onextRM,       // [c][b][S+1] or logits[b][C]
    int S, int ntiles, int is_last)
{
    constexpr int ROWS = K_ / UPB;
    constexpr int QPR  = DIN / 4;
    constexpr int QSH  = (DIN == 512) ? 7 : (DIN == 256) ? 6 : 4;
    constexpr int ITER = ROWS * QPR / 256;

    __shared__ float diff_s[B_];
    __shared__ float dw_s[K_];
    __shared__ int   win_s[K_];

    const int bid = blockIdx.x;
    const int tid = threadIdx.x;
    const int b   = tid;

    if (bid < ntiles) {
        // ---- fin: write layer outputs ----
        const int tile = bid;
        const int c    = tile / S;
        const int s    = tile - c * S;
        float dot = 0.0f;
#pragma unroll
        for (int j = 0; j < KSPL; ++j)
            dot += pdot[((size_t)tile * KSPL + j) * B_ + b];
        float outv = clampf(dot, LMIN_, LMAX_);
        if (is_last) {
            onextRM[(size_t)b * C_ + c] = outv;
        } else {
            onextT[((size_t)c * (S + 1) + (s + 1)) * B_ + b] = outv;   // coalesced
            onextRM[((size_t)c * B_ + b) * (size_t)(S + 1) + (s + 1)] = outv;
        }
        return;
    }

    // ---- update: inline winner/dw, then stream ROWS rows ----
    const int ub   = bid - ntiles;
    const int tile = ub / UPB;
    const int sub  = ub - tile * UPB;
    const int c    = tile / S;

    if (tid < K_) win_s[tid] = -1;

    float dot = 0.0f;
#pragma unroll
    for (int j = 0; j < KSPL; ++j)
        dot += pdot[((size_t)tile * KSPL + j) * B_ + b];
    float outv = clampf(dot, LMIN_, LMAX_);
    float tg = (target[b] == c) ? 1.0f : 0.0f;
    diff_s[b] = 1.0f / (1.0f + expf(-outv)) - tg;
    const int myrow = idx_buf[(size_t)tile * B_ + b];
    __syncthreads();
    atomicMax(&win_s[myrow], b);         // last-b-wins == max b
    __syncthreads();
    if (tid < K_) {
        int bw = win_s[tid];
        dw_s[tid] = (bw >= 0) ? LR_ * diff_s[bw] : 0.0f;
    }
    __syncthreads();

    const int r0 = sub * ROWS;
    const float* wp  = w  + ((size_t)tile * K_ + r0) * DIN;
    float*       nwp = nw + ((size_t)tile * K_ + r0) * DIN;
    const float* lgc = lgRM + (size_t)c * lg_sc;
#pragma unroll
    for (int j = 0; j < ITER; ++j) {
        int Q   = tid + 256 * j;
        int row = Q >> QSH;
        int col = (Q & (QPR - 1)) << 2;
        float4 wv = *(const float4*)(wp + (size_t)row * DIN + col);
        int bw = win_s[r0 + row];
        if (bw >= 0) {
            float d = dw_s[r0 + row];
            const float4 lv = *(const float4*)(lgc + (size_t)bw * DIN + col);
            wv.x = clampf(wv.x - d * lv.x, -WCLIP_, WCLIP_);
            wv.y = clampf(wv.y - d * lv.y, -WCLIP_, WCLIP_);
            wv.z = clampf(wv.z - d * lv.z, -WCLIP_, WCLIP_);
            wv.w = clampf(wv.w - d * lv.w, -WCLIP_, WCLIP_);
        }
        v4f o = {wv.x, wv.y, wv.z, wv.w};
        __builtin_nontemporal_store(o, (v4f*)(nwp + (size_t)row * DIN + col));
    }
}

extern "C" void kernel_launch(void* const* d_in, const int* in_sizes, int n_in,
                              void* d_out, int out_size, void* d_ws, size_t ws_size,
                              hipStream_t stream) {
    const float* x      = (const float*)d_in[0];
    const int*   target = (const int*)  d_in[1];
    const float* cmaps1 = (const float*)d_in[2];
    const float* w1     = (const float*)d_in[3];
    const float* bias1  = (const float*)d_in[4];
    const float* cmaps2 = (const float*)d_in[5];
    const float* w2     = (const float*)d_in[6];
    const float* bias2  = (const float*)d_in[7];
    const float* cmaps3 = (const float*)d_in[8];
    const float* w3     = (const float*)d_in[9];
    float* out = (float*)d_out;

    float* xT      = (float*)d_ws;                           // 131072
    float* l0      = xT     + (size_t)IN_ * B_;              // 131072
    float* l0T     = l0     + (size_t)B_ * IN_;              // 131072
    float* out1T   = l0T    + (size_t)IN_ * B_;              // 262144
    float* out1RM  = out1T  + (size_t)C_ * (S1_ + 1) * B_;   // 262144
    float* out2T   = out1RM + (size_t)C_ * B_ * (S1_ + 1);   // 65536
    float* out2RM  = out2T  + (size_t)C_ * (S2_ + 1) * B_;   // 65536
    float* pdot    = out2RM + (size_t)C_ * B_ * (S2_ + 1);   // NBLK1*8*B
    int*   idx_buf = (int*)(pdot + (size_t)NBLK1 * 8 * B_);  // NBLK_ALL*B

    float* logits = out;
    float* nw1 = out + (size_t)B_ * C_;
    float* nw2 = nw1 + (size_t)C_ * S1_ * K_ * IN_;
    float* nw3 = nw2 + (size_t)C_ * S2_ * K_ * (S1_ + 1);

    prep_kernel<<<dim3(128), dim3(256), 0, stream>>>(
        x, bias1, bias2, xT, l0, l0T, out1T, out1RM, out2T, out2RM);

    route_kernel<<<dim3(NBLK_ALL), dim3(256), 0, stream>>>(
        xT, cmaps1, cmaps2, cmaps3, idx_buf);

    const int* idx1 = idx_buf;
    const int* idx2 = idx_buf + (size_t)NBLK1 * B_;
    const int* idx3 = idx_buf + (size_t)(NBLK1 + NBLK2) * B_;

    // ---- layer 1 (DIN=512, lg = l0/l0T, c-stride 0) ----
    dot_kernel<512, 8><<<dim3(NBLK1 * 8), dim3(256), 0, stream>>>(
        l0T, 0L, w1, idx1, pdot, S1_);
    finup_kernel<512, 8, 4><<<dim3(NBLK1 * 5), dim3(256), 0, stream>>>(
        pdot, idx1, target, l0, 0L, w1, nw1, out1T, out1RM, S1_, NBLK1, 0);

    // ---- layer 2 (DIN=256, lg = out1) ----
    dot_kernel<256, 4><<<dim3(NBLK2 * 4), dim3(256), 0, stream>>>(
        out1T, (long)(S1_ + 1) * B_, w2, idx2, pdot, S2_);
    finup_kernel<256, 4, 2><<<dim3(NBLK2 * 3), dim3(256), 0, stream>>>(
        pdot, idx2, target, out1RM, (long)B_ * (S1_ + 1), w2, nw2, out2T, out2RM, S2_, NBLK2, 0);

    // ---- layer 3 (DIN=64, lg = out2) ----
    dot_kernel<64, 1><<<dim3(NBLK3), dim3(256), 0, stream>>>(
        out2T, (long)(S2_ + 1) * B_, w3, idx3, pdot, 1);
    finup_kernel<64, 1, 1><<<dim3(NBLK3 * 2), dim3(256), 0, stream>>>(
        pdot, idx3, target, out2RM, (long)B_ * (S2_ + 1), w3, nw3, nullptr, logits, 1, NBLK3, 1);
}

// Round 11
// 138.177 us; speedup vs baseline: 2.4560x; 1.0143x over previous
//
#include <hip/hip_runtime.h>
#include <math.h>

#define B_   256
#define IN_  512
#define C_   4
#define M_   6
#define K_   64
#define S1_  255
#define S2_  63

#define NBLK1 (C_ * S1_)                 // 1020
#define NBLK2 (C_ * S2_)                 // 252
#define NBLK3 (C_)                       // 4
#define NBLK_ALL (NBLK1 + NBLK2 + NBLK3) // 1276

#define LMIN_ (-6.906754778648554f)
#define LMAX_ ( 6.906754778648554f)
#define LR_   0.001f
#define WCLIP_ 5.0f

typedef float v4f __attribute__((ext_vector_type(4)));

__device__ __forceinline__ float clampf(float v, float lo, float hi) {
    return fminf(fmaxf(v, lo), hi);
}

// One-time prep: xT[i][b], l0[b][i], l0T[i][b]; bias rows of out1/out2.
__global__ __launch_bounds__(256) void prep_kernel(const float* __restrict__ x,
                                                   const float* __restrict__ bias1,
                                                   const float* __restrict__ bias2,
                                                   float* __restrict__ xT,
                                                   float* __restrict__ l0,
                                                   float* __restrict__ l0T,
                                                   float* __restrict__ out1T,
                                                   float* __restrict__ out1RM,
                                                   float* __restrict__ out2T,
                                                   float* __restrict__ out2RM) {
    __shared__ float tx_[32][33];
    __shared__ float tl_[32][33];
    const int i0 = (blockIdx.x & 15) * 32;
    const int b0 = (blockIdx.x >> 4) * 32;
    const int tx = threadIdx.x & 31;
    const int ty = threadIdx.x >> 5;
#pragma unroll
    for (int r = 0; r < 4; ++r) {
        int bb = b0 + ty + 8 * r;
        int ii = i0 + tx;
        float xv = x[(size_t)bb * IN_ + ii];
        float xc = clampf(xv, 0.001f, 0.999f);
        float lv = (ii == 0) ? 0.0f : logf(xc / (1.0f - xc));
        l0[(size_t)bb * IN_ + ii] = lv;
        tx_[ty + 8 * r][tx] = xv;
        tl_[ty + 8 * r][tx] = lv;
    }
    __syncthreads();
#pragma unroll
    for (int r = 0; r < 4; ++r) {
        int ii = i0 + ty + 8 * r;
        int bb = b0 + tx;
        xT[(size_t)ii * B_ + bb]  = tx_[tx][ty + 8 * r];
        l0T[(size_t)ii * B_ + bb] = tl_[tx][ty + 8 * r];
    }
    int gid = blockIdx.x * 256 + threadIdx.x;
    if (gid < C_ * B_) {
        int c = gid >> 8, b = gid & 255;
        float b1 = bias1[c], b2 = bias2[c];
        out1T[((size_t)c * (S1_ + 1)) * B_ + b] = b1;
        out1RM[((size_t)c * B_ + b) * (S1_ + 1)] = b1;
        out2T[((size_t)c * (S2_ + 1)) * B_ + b] = b2;
        out2RM[((size_t)c * B_ + b) * (S2_ + 1)] = b2;
    }
}

// Routing: block = 2 tiles, 4 waves split k into 128-wide quarters.
// cmaps via wave-uniform s_loads; xT coalesced (read once per block for both
// tiles -> halves L2 traffic); LDS combine in fixed order.
__global__ __launch_bounds__(256) void route_kernel(
    const float* __restrict__ xT,       // [IN][B]
    const float* __restrict__ cmaps1,
    const float* __restrict__ cmaps2,
    const float* __restrict__ cmaps3,
    int* __restrict__ idx_buf)          // [NBLK_ALL][B]
{
    __shared__ float sacc[3][2][M_][B_];   // 36 KB
    const int wv   = __builtin_amdgcn_readfirstlane(threadIdx.x >> 6); // wave-uniform
    const int lane = threadIdx.x & 63;
    const int t0   = blockIdx.x * 2;

    const float* cmp[2];
#pragma unroll
    for (int u = 0; u < 2; ++u) {
        int bid = t0 + u;
        if (bid < NBLK1)              cmp[u] = cmaps1 + (size_t)bid * M_ * IN_;
        else if (bid < NBLK1 + NBLK2) cmp[u] = cmaps2 + (size_t)(bid - NBLK1) * M_ * IN_;
        else                          cmp[u] = cmaps3 + (size_t)(bid - NBLK1 - NBLK2) * M_ * IN_;
    }

    float acc[2][4][M_];                // b = 64*jb + lane
#pragma unroll
    for (int u = 0; u < 2; ++u)
#pragma unroll
        for (int jb = 0; jb < 4; ++jb)
#pragma unroll
            for (int m = 0; m < M_; ++m) acc[u][jb][m] = 0.0f;

    const int kw = wv * 128;
    for (int k0 = kw; k0 < kw + 128; k0 += 8) {
        float xv[8][4];
#pragma unroll
        for (int j = 0; j < 8; ++j)
#pragma unroll
            for (int jb = 0; jb < 4; ++jb)
                xv[j][jb] = xT[(size_t)(k0 + j) * B_ + 64 * jb + lane];  // coalesced
#pragma unroll
        for (int j = 0; j < 8; ++j)
#pragma unroll
            for (int u = 0; u < 2; ++u)
#pragma unroll
                for (int m = 0; m < M_; ++m) {
                    float cv = cmp[u][(size_t)m * IN_ + k0 + j];         // s_load
#pragma unroll
                    for (int jb = 0; jb < 4; ++jb)
                        acc[u][jb][m] = fmaf(cv, xv[j][jb], acc[u][jb][m]);
                }
    }

    if (wv > 0) {
#pragma unroll
        for (int u = 0; u < 2; ++u)
#pragma unroll
            for (int jb = 0; jb < 4; ++jb)
#pragma unroll
                for (int m = 0; m < M_; ++m)
                    sacc[wv - 1][u][m][64 * jb + lane] = acc[u][jb][m];
    }
    __syncthreads();
    if (wv == 0) {
#pragma unroll
        for (int u = 0; u < 2; ++u)
#pragma unroll
            for (int jb = 0; jb < 4; ++jb) {
                int b = 64 * jb + lane;
                int myidx = 0;
#pragma unroll
                for (int m = 0; m < M_; ++m) {
                    float t = acc[u][jb][m] + sacc[0][u][m][b] + sacc[1][u][m][b] + sacc[2][u][m][b];
                    myidx |= (t > 0.0f) ? (1 << m) : 0;
                }
                idx_buf[(size_t)(t0 + u) * B_ + b] = myidx;
            }
    }
}

// ---- device bodies shared by standalone & mixed kernels ----

template<int DIN, int KSPL>
__device__ __forceinline__ void dot_body(
    int bid,
    const float* __restrict__ lgT, long lgT_sc,   // lgT[c*sc + k*B + b]
    const float* __restrict__ w,
    const int* __restrict__ idx_buf,
    float* __restrict__ pdot,          // [tiles][KSPL][B]
    int S, float* wl)                  // wl: K_*65 floats LDS
{
    constexpr int KR  = DIN / KSPL;    // = 64
    static_assert(KR == 64, "k-slice must be 64");
    constexpr int PAD = 65;

    const int tile = bid / KSPL;
    const int ks   = bid % KSPL;
    const int c    = tile / S;
    const int tid  = threadIdx.x;
    const int b    = tid;
    const int k0   = ks * KR;

    const int myrow = idx_buf[(size_t)tile * B_ + b];

    // stage w 64x64 slice: coalesced f4 global loads, scalar LDS writes
    const float* wp = w + (size_t)tile * K_ * DIN + k0;
#pragma unroll
    for (int j = 0; j < 4; ++j) {
        int f   = tid + 256 * j;
        int row = f >> 4;
        int q   = (f & 15) << 2;
        float4 v = *(const float4*)(wp + (size_t)row * DIN + q);
        wl[row * PAD + q + 0] = v.x;
        wl[row * PAD + q + 1] = v.y;
        wl[row * PAD + q + 2] = v.z;
        wl[row * PAD + q + 3] = v.w;
    }
    __syncthreads();

    const float* lgp = lgT + (size_t)c * lgT_sc + (size_t)k0 * B_ + b;
    const float* wr  = wl + myrow * PAD;
    float dot = 0.0f;
    for (int kk = 0; kk < KR; kk += 8) {
        float lv[8];
#pragma unroll
        for (int t = 0; t < 8; ++t) lv[t] = lgp[(size_t)(kk + t) * B_];  // coalesced
#pragma unroll
        for (int t = 0; t < 8; ++t) dot = fmaf(wr[kk + t], lv[t], dot);  // broadcast/2-way
    }
    pdot[((size_t)tile * KSPL + ks) * B_ + b] = dot;
}

template<int DIN>
__device__ __forceinline__ void update_body(
    int ub,
    const float* __restrict__ w,
    const float* __restrict__ lgRM, long lg_sc,
    const int* __restrict__ win_g,     // [tiles*K]
    const float* __restrict__ dw_g,
    float* __restrict__ nw,
    int SK)                            // S * K_ (rows per class)
{
    constexpr int QPR = DIN / 4;
    constexpr int QSH = (DIN == 512) ? 7 : (DIN == 256) ? 6 : 4;
    const int base = ub * 2048 + threadIdx.x;
#pragma unroll
    for (int j = 0; j < 8; ++j) {
        int Q   = base + j * 256;
        int row = Q >> QSH;
        int col = (Q & (QPR - 1)) << 2;
        float4 wv = *(const float4*)(w + (size_t)row * DIN + col);
        int bw = win_g[row];
        if (bw >= 0) {
            float d = dw_g[row];
            int cc  = row / SK;
            const float4 lv = *(const float4*)(lgRM + (size_t)cc * lg_sc + (size_t)bw * DIN + col);
            wv.x = clampf(wv.x - d * lv.x, -WCLIP_, WCLIP_);
            wv.y = clampf(wv.y - d * lv.y, -WCLIP_, WCLIP_);
            wv.z = clampf(wv.z - d * lv.z, -WCLIP_, WCLIP_);
            wv.w = clampf(wv.w - d * lv.w, -WCLIP_, WCLIP_);
        }
        v4f o = {wv.x, wv.y, wv.z, wv.w};
        __builtin_nontemporal_store(o, (v4f*)(nw + (size_t)row * DIN + col));
    }
}

// Standalone dot (layer 1).
template<int DIN, int KSPL>
__global__ __launch_bounds__(256) void dot_kernel(
    const float* __restrict__ lgT, long lgT_sc,
    const float* __restrict__ w,
    const int* __restrict__ idx_buf,
    float* __restrict__ pdot, int S)
{
    __shared__ float wl[K_ * 65];
    dot_body<DIN, KSPL>(blockIdx.x, lgT, lgT_sc, w, idx_buf, pdot, S, wl);
}

// fin: sum partials (fixed order), clip, outputs (both layouts), diff,
// winner, per-row dw -> global (layers 1 & 2).
__global__ __launch_bounds__(256) void fin_kernel(
    const float* __restrict__ pdot, int KSPL,
    const int* __restrict__ idx_buf,
    const int* __restrict__ target,
    float* __restrict__ onextT,        // [c][S+1][b]
    float* __restrict__ onextRM,       // [c][b][S+1]
    int* __restrict__ win_g,           // [tiles][K]
    float* __restrict__ dw_g,          // [tiles][K]
    int S)
{
    __shared__ float diff_s[B_];
    __shared__ int   win_s[K_];
    const int tile = blockIdx.x;
    const int c    = tile / S;
    const int s    = tile - c * S;
    const int b    = threadIdx.x;

    if (b < K_) win_s[b] = -1;

    float dot = 0.0f;
    for (int j = 0; j < KSPL; ++j)
        dot += pdot[((size_t)tile * KSPL + j) * B_ + b];

    float outv = clampf(dot, LMIN_, LMAX_);
    onextT[((size_t)c * (S + 1) + (s + 1)) * B_ + b] = outv;   // coalesced
    onextRM[((size_t)c * B_ + b) * (size_t)(S + 1) + (s + 1)] = outv;

    float tg = (target[b] == c) ? 1.0f : 0.0f;
    diff_s[b] = 1.0f / (1.0f + expf(-outv)) - tg;
    const int myrow = idx_buf[(size_t)tile * B_ + b];
    __syncthreads();
    atomicMax(&win_s[myrow], b);         // last-b-wins == max b
    __syncthreads();
    if (b < K_) {
        int bw = win_s[b];
        win_g[(size_t)tile * K_ + b] = bw;
        dw_g[(size_t)tile * K_ + b]  = (bw >= 0) ? LR_ * diff_s[bw] : 0.0f;
    }
}

// Mixed launch: first ndot blocks run dot (next layer), rest run update
// (previous layer's weight stream) -> latency-bound dot hides under BW stream.
template<int DIN_D, int KSPL_D, int DIN_U>
__global__ __launch_bounds__(256) void mix_kernel(
    const float* __restrict__ lgT, long lgT_sc,
    const float* __restrict__ wD,
    const int* __restrict__ idxD,
    float* __restrict__ pdot, int SD, int ndot,
    const float* __restrict__ wU,
    const float* __restrict__ lgRM, long lg_sc,
    const int* __restrict__ win_g,
    const float* __restrict__ dw_g,
    float* __restrict__ nwU, int SKU)
{
    __shared__ float wl[K_ * 65];
    if ((int)blockIdx.x < ndot)
        dot_body<DIN_D, KSPL_D>(blockIdx.x, lgT, lgT_sc, wD, idxD, pdot, SD, wl);
    else
        update_body<DIN_U>(blockIdx.x - ndot, wU, lgRM, lg_sc, win_g, dw_g, nwU, SKU);
}

// Layer-3 fin + update fused (4 blocks, one per class).
__global__ __launch_bounds__(256) void fin3u_kernel(
    const float* __restrict__ pdot,    // [C][B], KSPL=1
    const int* __restrict__ idx3,
    const int* __restrict__ target,
    const float* __restrict__ lgRM, long lg_sc,   // out2RM
    const float* __restrict__ w3,
    float* __restrict__ nw3,
    float* __restrict__ logits)        // [B][C]
{
    __shared__ float diff_s[B_];
    __shared__ float dw_s[K_];
    __shared__ int   win_s[K_];
    const int c = blockIdx.x;
    const int b = threadIdx.x;

    if (b < K_) win_s[b] = -1;

    float outv = clampf(pdot[(size_t)c * B_ + b], LMIN_, LMAX_);
    logits[(size_t)b * C_ + c] = outv;
    float tg = (target[b] == c) ? 1.0f : 0.0f;
    diff_s[b] = 1.0f / (1.0f + expf(-outv)) - tg;
    const int myrow = idx3[(size_t)c * B_ + b];
    __syncthreads();
    atomicMax(&win_s[myrow], b);
    __syncthreads();
    if (b < K_) {
        int bw = win_s[b];
        dw_s[b] = (bw >= 0) ? LR_ * diff_s[bw] : 0.0f;
    }
    __syncthreads();

    const float* lgc = lgRM + (size_t)c * lg_sc;
    const float* wp  = w3  + (size_t)c * K_ * 64;
    float*       nwp = nw3 + (size_t)c * K_ * 64;
#pragma unroll
    for (int j = 0; j < 4; ++j) {
        int Q   = b + 256 * j;             // 1024 f4 = 64 rows x 16 quads
        int row = Q >> 4;
        int col = (Q & 15) << 2;
        float4 wv = *(const float4*)(wp + row * 64 + col);
        int bw = win_s[row];
        if (bw >= 0) {
            float d = dw_s[row];
            const float4 lv = *(const float4*)(lgc + (size_t)bw * 64 + col);
            wv.x = clampf(wv.x - d * lv.x, -WCLIP_, WCLIP_);
            wv.y = clampf(wv.y - d * lv.y, -WCLIP_, WCLIP_);
            wv.z = clampf(wv.z - d * lv.z, -WCLIP_, WCLIP_);
            wv.w = clampf(wv.w - d * lv.w, -WCLIP_, WCLIP_);
        }
        v4f o = {wv.x, wv.y, wv.z, wv.w};
        __builtin_nontemporal_store(o, (v4f*)(nwp + row * 64 + col));
    }
}

extern "C" void kernel_launch(void* const* d_in, const int* in_sizes, int n_in,
                              void* d_out, int out_size, void* d_ws, size_t ws_size,
                              hipStream_t stream) {
    const float* x      = (const float*)d_in[0];
    const int*   target = (const int*)  d_in[1];
    const float* cmaps1 = (const float*)d_in[2];
    const float* w1     = (const float*)d_in[3];
    const float* bias1  = (const float*)d_in[4];
    const float* cmaps2 = (const float*)d_in[5];
    const float* w2     = (const float*)d_in[6];
    const float* bias2  = (const float*)d_in[7];
    const float* cmaps3 = (const float*)d_in[8];
    const float* w3     = (const float*)d_in[9];
    float* out = (float*)d_out;

    float* xT      = (float*)d_ws;                           // 131072
    float* l0      = xT     + (size_t)IN_ * B_;              // 131072
    float* l0T     = l0     + (size_t)B_ * IN_;              // 131072
    float* out1T   = l0T    + (size_t)IN_ * B_;              // 262144
    float* out1RM  = out1T  + (size_t)C_ * (S1_ + 1) * B_;   // 262144
    float* out2T   = out1RM + (size_t)C_ * B_ * (S1_ + 1);   // 65536
    float* out2RM  = out2T  + (size_t)C_ * (S2_ + 1) * B_;   // 65536
    float* pdot    = out2RM + (size_t)C_ * B_ * (S2_ + 1);   // NBLK1*8*B
    float* dw_g    = pdot   + (size_t)NBLK1 * 8 * B_;        // NBLK_ALL*K
    int*   win_g   = (int*)(dw_g + (size_t)NBLK_ALL * K_);   // NBLK_ALL*K
    int*   idx_buf = (int*)(win_g + (size_t)NBLK_ALL * K_);  // NBLK_ALL*B

    float* logits = out;
    float* nw1 = out + (size_t)B_ * C_;
    float* nw2 = nw1 + (size_t)C_ * S1_ * K_ * IN_;
    float* nw3 = nw2 + (size_t)C_ * S2_ * K_ * (S1_ + 1);

    const int* idx1 = idx_buf;
    const int* idx2 = idx_buf + (size_t)NBLK1 * B_;
    const int* idx3 = idx_buf + (size_t)(NBLK1 + NBLK2) * B_;
    int*   win1 = win_g;                         float* dw1 = dw_g;
    int*   win2 = win_g + NBLK1 * K_;            float* dw2 = dw_g + NBLK1 * K_;

    prep_kernel<<<dim3(128), dim3(256), 0, stream>>>(
        x, bias1, bias2, xT, l0, l0T, out1T, out1RM, out2T, out2RM);

    route_kernel<<<dim3(NBLK_ALL / 2), dim3(256), 0, stream>>>(
        xT, cmaps1, cmaps2, cmaps3, idx_buf);

    // ---- layer 1 dot ----
    dot_kernel<512, 8><<<dim3(NBLK1 * 8), dim3(256), 0, stream>>>(
        l0T, 0L, w1, idx1, pdot, S1_);
    fin_kernel<<<dim3(NBLK1), dim3(256), 0, stream>>>(
        pdot, 8, idx1, target, out1T, out1RM, win1, dw1, S1_);

    // ---- dot2 (critical path) || update1 (w1 stream) ----
    mix_kernel<256, 4, 512><<<dim3(NBLK2 * 4 + NBLK1 * 4), dim3(256), 0, stream>>>(
        out1T, (long)(S1_ + 1) * B_, w2, idx2, pdot, S2_, NBLK2 * 4,
        w1, l0, 0L, win1, dw1, nw1, S1_ * K_);
    fin_kernel<<<dim3(NBLK2), dim3(256), 0, stream>>>(
        pdot, 4, idx2, target, out2T, out2RM, win2, dw2, S2_);

    // ---- dot3 || update2 ----
    mix_kernel<64, 1, 256><<<dim3(NBLK3 + NBLK2 * 2), dim3(256), 0, stream>>>(
        out2T, (long)(S2_ + 1) * B_, w3, idx3, pdot, 1, NBLK3,
        w2, out1RM, (long)B_ * (S1_ + 1), win2, dw2, nw2, S2_ * K_);

    // ---- fin3 + update3 fused ----
    fin3u_kernel<<<dim3(NBLK3), dim3(256), 0, stream>>>(
        pdot, idx3, target, out2RM, (long)B_ * (S2_ + 1), w3, nw3, logits);
}

// Round 12
// 126.637 us; speedup vs baseline: 2.6798x; 1.0911x over previous
//
#include <hip/hip_runtime.h>
#include <math.h>

#define B_   256
#define IN_  512
#define C_   4
#define M_   6
#define K_   64
#define S1_  255
#define S2_  63

#define NBLK1 (C_ * S1_)                 // 1020
#define NBLK2 (C_ * S2_)                 // 252
#define NBLK3 (C_)                       // 4
#define NBLK_ALL (NBLK1 + NBLK2 + NBLK3) // 1276

#define LMIN_ (-6.906754778648554f)
#define LMAX_ ( 6.906754778648554f)
#define LR_   0.001f
#define WCLIP_ 5.0f

typedef float v4f __attribute__((ext_vector_type(4)));

__device__ __forceinline__ float clampf(float v, float lo, float hi) {
    return fminf(fmaxf(v, lo), hi);
}

// One-time prep: xT[i][b], l0[b][i], l0T[i][b]; bias rows of out1/out2.
__global__ __launch_bounds__(256) void prep_kernel(const float* __restrict__ x,
                                                   const float* __restrict__ bias1,
                                                   const float* __restrict__ bias2,
                                                   float* __restrict__ xT,
                                                   float* __restrict__ l0,
                                                   float* __restrict__ l0T,
                                                   float* __restrict__ out1T,
                                                   float* __restrict__ out1RM,
                                                   float* __restrict__ out2T,
                                                   float* __restrict__ out2RM) {
    __shared__ float tx_[32][33];
    __shared__ float tl_[32][33];
    const int i0 = (blockIdx.x & 15) * 32;
    const int b0 = (blockIdx.x >> 4) * 32;
    const int tx = threadIdx.x & 31;
    const int ty = threadIdx.x >> 5;
#pragma unroll
    for (int r = 0; r < 4; ++r) {
        int bb = b0 + ty + 8 * r;
        int ii = i0 + tx;
        float xv = x[(size_t)bb * IN_ + ii];
        float xc = clampf(xv, 0.001f, 0.999f);
        float lv = (ii == 0) ? 0.0f : logf(xc / (1.0f - xc));
        l0[(size_t)bb * IN_ + ii] = lv;
        tx_[ty + 8 * r][tx] = xv;
        tl_[ty + 8 * r][tx] = lv;
    }
    __syncthreads();
#pragma unroll
    for (int r = 0; r < 4; ++r) {
        int ii = i0 + ty + 8 * r;
        int bb = b0 + tx;
        xT[(size_t)ii * B_ + bb]  = tx_[tx][ty + 8 * r];
        l0T[(size_t)ii * B_ + bb] = tl_[tx][ty + 8 * r];
    }
    int gid = blockIdx.x * 256 + threadIdx.x;
    if (gid < C_ * B_) {
        int c = gid >> 8, b = gid & 255;
        float b1 = bias1[c], b2 = bias2[c];
        out1T[((size_t)c * (S1_ + 1)) * B_ + b] = b1;
        out1RM[((size_t)c * B_ + b) * (S1_ + 1)] = b1;
        out2T[((size_t)c * (S2_ + 1)) * B_ + b] = b2;
        out2RM[((size_t)c * B_ + b) * (S2_ + 1)] = b2;
    }
}

// Routing: block = 2 tiles, 4 waves split k into 128-wide quarters.
__global__ __launch_bounds__(256) void route_kernel(
    const float* __restrict__ xT,       // [IN][B]
    const float* __restrict__ cmaps1,
    const float* __restrict__ cmaps2,
    const float* __restrict__ cmaps3,
    int* __restrict__ idx_buf)          // [NBLK_ALL][B]
{
    __shared__ float sacc[3][2][M_][B_];   // 36 KB
    const int wv   = __builtin_amdgcn_readfirstlane(threadIdx.x >> 6);
    const int lane = threadIdx.x & 63;
    const int t0   = blockIdx.x * 2;

    const float* cmp[2];
#pragma unroll
    for (int u = 0; u < 2; ++u) {
        int bid = t0 + u;
        if (bid < NBLK1)              cmp[u] = cmaps1 + (size_t)bid * M_ * IN_;
        else if (bid < NBLK1 + NBLK2) cmp[u] = cmaps2 + (size_t)(bid - NBLK1) * M_ * IN_;
        else                          cmp[u] = cmaps3 + (size_t)(bid - NBLK1 - NBLK2) * M_ * IN_;
    }

    float acc[2][4][M_];
#pragma unroll
    for (int u = 0; u < 2; ++u)
#pragma unroll
        for (int jb = 0; jb < 4; ++jb)
#pragma unroll
            for (int m = 0; m < M_; ++m) acc[u][jb][m] = 0.0f;

    const int kw = wv * 128;
    for (int k0 = kw; k0 < kw + 128; k0 += 8) {
        float xv[8][4];
#pragma unroll
        for (int j = 0; j < 8; ++j)
#pragma unroll
            for (int jb = 0; jb < 4; ++jb)
                xv[j][jb] = xT[(size_t)(k0 + j) * B_ + 64 * jb + lane];
#pragma unroll
        for (int j = 0; j < 8; ++j)
#pragma unroll
            for (int u = 0; u < 2; ++u)
#pragma unroll
                for (int m = 0; m < M_; ++m) {
                    float cv = cmp[u][(size_t)m * IN_ + k0 + j];
#pragma unroll
                    for (int jb = 0; jb < 4; ++jb)
                        acc[u][jb][m] = fmaf(cv, xv[j][jb], acc[u][jb][m]);
                }
    }

    if (wv > 0) {
#pragma unroll
        for (int u = 0; u < 2; ++u)
#pragma unroll
            for (int jb = 0; jb < 4; ++jb)
#pragma unroll
                for (int m = 0; m < M_; ++m)
                    sacc[wv - 1][u][m][64 * jb + lane] = acc[u][jb][m];
    }
    __syncthreads();
    if (wv == 0) {
#pragma unroll
        for (int u = 0; u < 2; ++u)
#pragma unroll
            for (int jb = 0; jb < 4; ++jb) {
                int b = 64 * jb + lane;
                int myidx = 0;
#pragma unroll
                for (int m = 0; m < M_; ++m) {
                    float t = acc[u][jb][m] + sacc[0][u][m][b] + sacc[1][u][m][b] + sacc[2][u][m][b];
                    myidx |= (t > 0.0f) ? (1 << m) : 0;
                }
                idx_buf[(size_t)(t0 + u) * B_ + b] = myidx;
            }
    }
}

// ---- fused dot+fin per tile: 512 threads = 2 k-halves x 256 b ----
template<int DIN>
__device__ __forceinline__ void dotfin_body(
    int tile,
    const float* __restrict__ lgT, long lgT_sc,   // lgT[c*sc + k*B + b]
    const float* __restrict__ w,
    const int* __restrict__ idx_buf,
    const int* __restrict__ target,
    float* __restrict__ onextT,        // [c][S+1][b]
    float* __restrict__ onextRM,       // [c][b][S+1]
    int* __restrict__ win_g,           // [tiles][K]
    float* __restrict__ dw_g,          // [tiles][K]
    int S,
    float* wl, float* part_s, float* diff_s, int* win_s)
{
    constexpr int HALF = DIN / 2;
    constexpr int NR   = HALF / 64;
    const int c   = tile / S;
    const int s   = tile - c * S;
    const int tid = threadIdx.x;
    const int kh  = __builtin_amdgcn_readfirstlane(tid >> 8);  // wave-uniform
    const int b   = tid & 255;

    if (tid < K_) win_s[tid] = -1;
    const int myrow = idx_buf[(size_t)tile * B_ + b];

    const float* wp  = w + (size_t)tile * K_ * DIN + kh * HALF;
    float*       dst = wl + kh * (K_ * 65);
    float dot = 0.0f;
#pragma unroll
    for (int r = 0; r < NR; ++r) {
        // stage 64x64 slice of this half: coalesced f4, pitch-65 scalar writes
        const float* src = wp + r * 64;
#pragma unroll
        for (int j = 0; j < 4; ++j) {
            int f   = b + 256 * j;
            int row = f >> 4;
            int q   = (f & 15) << 2;
            float4 v = *(const float4*)(src + (size_t)row * DIN + q);
            dst[row * 65 + q + 0] = v.x;
            dst[row * 65 + q + 1] = v.y;
            dst[row * 65 + q + 2] = v.z;
            dst[row * 65 + q + 3] = v.w;
        }
        __syncthreads();
        const float* lgp = lgT + (size_t)c * lgT_sc + (size_t)(kh * HALF + r * 64) * B_ + b;
        const float* wr  = dst + myrow * 65;
        for (int kk = 0; kk < 64; kk += 8) {
            float lv[8];
#pragma unroll
            for (int t = 0; t < 8; ++t) lv[t] = lgp[(size_t)(kk + t) * B_];  // coalesced
#pragma unroll
            for (int t = 0; t < 8; ++t) dot = fmaf(wr[kk + t], lv[t], dot);
        }
        __syncthreads();
    }
    if (kh == 1) part_s[b] = dot;
    __syncthreads();
    if (kh == 0) {
        float total = dot + part_s[b];
        float outv = clampf(total, LMIN_, LMAX_);
        onextT[((size_t)c * (S + 1) + (s + 1)) * B_ + b] = outv;   // coalesced
        onextRM[((size_t)c * B_ + b) * (size_t)(S + 1) + (s + 1)] = outv;
        float tg = (target[b] == c) ? 1.0f : 0.0f;
        diff_s[b] = 1.0f / (1.0f + expf(-outv)) - tg;
        atomicMax(&win_s[myrow], b);       // last-b-wins == max b
    }
    __syncthreads();
    if (tid < K_) {
        int bw = win_s[tid];
        win_g[(size_t)tile * K_ + tid] = bw;
        dw_g[(size_t)tile * K_ + tid]  = (bw >= 0) ? LR_ * diff_s[bw] : 0.0f;
    }
}

// stream update, 512 threads: block -> 2048 float4.
template<int DIN>
__device__ __forceinline__ void update_body(
    int ub,
    const float* __restrict__ w,
    const float* __restrict__ lgRM, long lg_sc,
    const int* __restrict__ win_g,
    const float* __restrict__ dw_g,
    float* __restrict__ nw,
    int SK)
{
    constexpr int QPR = DIN / 4;
    constexpr int QSH = (DIN == 512) ? 7 : 6;
    const int base = ub * 2048 + threadIdx.x;
#pragma unroll
    for (int j = 0; j < 4; ++j) {
        int Q   = base + j * 512;
        int row = Q >> QSH;
        int col = (Q & (QPR - 1)) << 2;
        float4 wv = *(const float4*)(w + (size_t)row * DIN + col);
        int bw = win_g[row];
        if (bw >= 0) {
            float d = dw_g[row];
            int cc  = row / SK;
            const float4 lv = *(const float4*)(lgRM + (size_t)cc * lg_sc + (size_t)bw * DIN + col);
            wv.x = clampf(wv.x - d * lv.x, -WCLIP_, WCLIP_);
            wv.y = clampf(wv.y - d * lv.y, -WCLIP_, WCLIP_);
            wv.z = clampf(wv.z - d * lv.z, -WCLIP_, WCLIP_);
            wv.w = clampf(wv.w - d * lv.w, -WCLIP_, WCLIP_);
        }
        v4f o = {wv.x, wv.y, wv.z, wv.w};
        __builtin_nontemporal_store(o, (v4f*)(nw + (size_t)row * DIN + col));
    }
}

// Layer-1 dot+fin standalone.
__global__ __launch_bounds__(512) void dotfin1_kernel(
    const float* __restrict__ l0T,
    const float* __restrict__ w1,
    const int* __restrict__ idx1,
    const int* __restrict__ target,
    float* __restrict__ out1T, float* __restrict__ out1RM,
    int* __restrict__ win1, float* __restrict__ dw1)
{
    __shared__ float wl[2 * K_ * 65];
    __shared__ float part_s[B_];
    __shared__ float diff_s[B_];
    __shared__ int   win_s[K_];
    dotfin_body<512>(blockIdx.x, l0T, 0L, w1, idx1, target,
                     out1T, out1RM, win1, dw1, S1_, wl, part_s, diff_s, win_s);
}

// mix2: first ndot blocks = layer-2 dot+fin; rest = layer-1 update stream.
__global__ __launch_bounds__(512) void mix2_kernel(
    const float* __restrict__ out1T,
    const float* __restrict__ w2,
    const int* __restrict__ idx2,
    const int* __restrict__ target,
    float* __restrict__ out2T, float* __restrict__ out2RM,
    int* __restrict__ win2, float* __restrict__ dw2,
    const float* __restrict__ w1,
    const float* __restrict__ l0,
    const int* __restrict__ win1, const float* __restrict__ dw1,
    float* __restrict__ nw1, int ndot)
{
    __shared__ float wl[2 * K_ * 65];
    __shared__ float part_s[B_];
    __shared__ float diff_s[B_];
    __shared__ int   win_s[K_];
    if ((int)blockIdx.x < ndot)
        dotfin_body<256>(blockIdx.x, out1T, (long)(S1_ + 1) * B_, w2, idx2, target,
                         out2T, out2RM, win2, dw2, S2_, wl, part_s, diff_s, win_s);
    else
        update_body<512>(blockIdx.x - ndot, w1, l0, 0L, win1, dw1, nw1, S1_ * K_);
}

// layer-3 full fusion: dot+fin+update from LDS (w3 read once). 512 threads.
__device__ __forceinline__ void dotfinup3_body(
    int c,
    const float* __restrict__ lgT, long lgT_sc,   // out2T
    const float* __restrict__ lgRM, long lg_sc,   // out2RM
    const float* __restrict__ w3,
    const int* __restrict__ idx3,
    const int* __restrict__ target,
    float* __restrict__ nw3,
    float* __restrict__ logits,
    float* wl /*2*K_*33*/, float* part_s, float* diff_s, float* dw_s, int* win_s)
{
    const int tid = threadIdx.x;
    const int kh  = __builtin_amdgcn_readfirstlane(tid >> 8);
    const int b   = tid & 255;
    if (tid < K_) win_s[tid] = -1;
    const int myrow = idx3[(size_t)c * B_ + b];

    const float* wp  = w3 + (size_t)c * K_ * 64 + kh * 32;
    float*       dst = wl + kh * (K_ * 33);
#pragma unroll
    for (int j = 0; j < 2; ++j) {
        int f   = b + 256 * j;         // 512 f4 = 64 rows x 8 quads
        int row = f >> 3;
        int q   = (f & 7) << 2;
        float4 v = *(const float4*)(wp + (size_t)row * 64 + q);
        dst[row * 33 + q + 0] = v.x;
        dst[row * 33 + q + 1] = v.y;
        dst[row * 33 + q + 2] = v.z;
        dst[row * 33 + q + 3] = v.w;
    }
    __syncthreads();
    const float* lgp = lgT + (size_t)c * lgT_sc + (size_t)(kh * 32) * B_ + b;
    const float* wr  = dst + myrow * 33;
    float dot = 0.0f;
    for (int kk = 0; kk < 32; kk += 8) {
        float lv[8];
#pragma unroll
        for (int t = 0; t < 8; ++t) lv[t] = lgp[(size_t)(kk + t) * B_];
#pragma unroll
        for (int t = 0; t < 8; ++t) dot = fmaf(wr[kk + t], lv[t], dot);
    }
    if (kh == 1) part_s[b] = dot;
    __syncthreads();
    if (kh == 0) {
        float total = dot + part_s[b];
        float outv = clampf(total, LMIN_, LMAX_);
        logits[(size_t)b * C_ + c] = outv;
        float tg = (target[b] == c) ? 1.0f : 0.0f;
        diff_s[b] = 1.0f / (1.0f + expf(-outv)) - tg;
        atomicMax(&win_s[myrow], b);
    }
    __syncthreads();
    if (tid < K_) dw_s[tid] = (win_s[tid] >= 0) ? LR_ * diff_s[win_s[tid]] : 0.0f;
    __syncthreads();

    const float* lgc = lgRM + (size_t)c * lg_sc;
    float* nwp = nw3 + (size_t)c * K_ * 64;
#pragma unroll
    for (int j = 0; j < 2; ++j) {
        int Q   = tid + 512 * j;       // 1024 f4 = 64 rows x 16 quads
        int row = Q >> 4;
        int col = (Q & 15) << 2;
        const float* wsrc = wl + (col >> 5) * (K_ * 33) + row * 33 + (col & 31);
        float4 wv = {wsrc[0], wsrc[1], wsrc[2], wsrc[3]};
        int bw = win_s[row];
        if (bw >= 0) {
            float d = dw_s[row];
            const float4 lv = *(const float4*)(lgc + (size_t)bw * 64 + col);
            wv.x = clampf(wv.x - d * lv.x, -WCLIP_, WCLIP_);
            wv.y = clampf(wv.y - d * lv.y, -WCLIP_, WCLIP_);
            wv.z = clampf(wv.z - d * lv.z, -WCLIP_, WCLIP_);
            wv.w = clampf(wv.w - d * lv.w, -WCLIP_, WCLIP_);
        }
        v4f o = {wv.x, wv.y, wv.z, wv.w};
        __builtin_nontemporal_store(o, (v4f*)(nwp + (size_t)row * 64 + col));
    }
}

// mix3: first 4 blocks = layer-3 full fusion; rest = layer-2 update stream.
__global__ __launch_bounds__(512) void mix3_kernel(
    const float* __restrict__ out2T,
    const float* __restrict__ out2RM,
    const float* __restrict__ w3,
    const int* __restrict__ idx3,
    const int* __restrict__ target,
    float* __restrict__ nw3,
    float* __restrict__ logits,
    const float* __restrict__ w2,
    const float* __restrict__ out1RM,
    const int* __restrict__ win2, const float* __restrict__ dw2,
    float* __restrict__ nw2, int ndot)
{
    __shared__ float wl[2 * K_ * 33];
    __shared__ float part_s[B_];
    __shared__ float diff_s[B_];
    __shared__ float dw_s[K_];
    __shared__ int   win_s[K_];
    if ((int)blockIdx.x < ndot)
        dotfinup3_body(blockIdx.x, out2T, (long)(S2_ + 1) * B_,
                       out2RM, (long)B_ * (S2_ + 1), w3, idx3, target,
                       nw3, logits, wl, part_s, diff_s, dw_s, win_s);
    else
        update_body<256>(blockIdx.x - ndot, w2, out1RM, (long)B_ * (S1_ + 1),
                         win2, dw2, nw2, S2_ * K_);
}

extern "C" void kernel_launch(void* const* d_in, const int* in_sizes, int n_in,
                              void* d_out, int out_size, void* d_ws, size_t ws_size,
                              hipStream_t stream) {
    const float* x      = (const float*)d_in[0];
    const int*   target = (const int*)  d_in[1];
    const float* cmaps1 = (const float*)d_in[2];
    const float* w1     = (const float*)d_in[3];
    const float* bias1  = (const float*)d_in[4];
    const float* cmaps2 = (const float*)d_in[5];
    const float* w2     = (const float*)d_in[6];
    const float* bias2  = (const float*)d_in[7];
    const float* cmaps3 = (const float*)d_in[8];
    const float* w3     = (const float*)d_in[9];
    float* out = (float*)d_out;

    float* xT      = (float*)d_ws;                           // 131072
    float* l0      = xT     + (size_t)IN_ * B_;              // 131072
    float* l0T     = l0     + (size_t)B_ * IN_;              // 131072
    float* out1T   = l0T    + (size_t)IN_ * B_;              // 262144
    float* out1RM  = out1T  + (size_t)C_ * (S1_ + 1) * B_;   // 262144
    float* out2T   = out1RM + (size_t)C_ * B_ * (S1_ + 1);   // 65536
    float* out2RM  = out2T  + (size_t)C_ * (S2_ + 1) * B_;   // 65536
    float* dw_g    = out2RM + (size_t)C_ * B_ * (S2_ + 1);   // NBLK_ALL*K
    int*   win_g   = (int*)(dw_g + (size_t)NBLK_ALL * K_);   // NBLK_ALL*K
    int*   idx_buf = (int*)(win_g + (size_t)NBLK_ALL * K_);  // NBLK_ALL*B

    float* logits = out;
    float* nw1 = out + (size_t)B_ * C_;
    float* nw2 = nw1 + (size_t)C_ * S1_ * K_ * IN_;
    float* nw3 = nw2 + (size_t)C_ * S2_ * K_ * (S1_ + 1);

    const int* idx1 = idx_buf;
    const int* idx2 = idx_buf + (size_t)NBLK1 * B_;
    const int* idx3 = idx_buf + (size_t)(NBLK1 + NBLK2) * B_;
    int*   win1 = win_g;                float* dw1 = dw_g;
    int*   win2 = win_g + NBLK1 * K_;   float* dw2 = dw_g + NBLK1 * K_;

    prep_kernel<<<dim3(128), dim3(256), 0, stream>>>(
        x, bias1, bias2, xT, l0, l0T, out1T, out1RM, out2T, out2RM);

    route_kernel<<<dim3(NBLK_ALL / 2), dim3(256), 0, stream>>>(
        xT, cmaps1, cmaps2, cmaps3, idx_buf);

    // layer-1 dot+fin (per-tile, pdot stays in LDS)
    dotfin1_kernel<<<dim3(NBLK1), dim3(512), 0, stream>>>(
        l0T, w1, idx1, target, out1T, out1RM, win1, dw1);

    // layer-2 dot+fin || layer-1 update stream
    mix2_kernel<<<dim3(NBLK2 + NBLK1 * 4), dim3(512), 0, stream>>>(
        out1T, w2, idx2, target, out2T, out2RM, win2, dw2,
        w1, l0, win1, dw1, nw1, NBLK2);

    // layer-3 dot+fin+update || layer-2 update stream
    mix3_kernel<<<dim3(NBLK3 + NBLK2 * 64 * 64 / 2048), dim3(512), 0, stream>>>(
        out2T, out2RM, w3, idx3, target, nw3, logits,
        w2, out1RM, win2, dw2, nw2, NBLK3);
}